// Round 1
// baseline (2710.772 us; speedup 1.0000x reference)
//
#include <hip/hip_runtime.h>
#include <math.h>

// ---------------------------------------------------------------------------
// MultiHeadFAVORAttention pipeline, all-f32 correctness-first implementation.
// B=2, S=4096, C=1024, H=16, Dh=64, G=3 gammas, Ms=256, GMs=768, NRF=256, L=64
// ---------------------------------------------------------------------------

// ======================== tiled GEMM (f32) =================================
// TM=128, TN=64, TK=16, 256 threads, each thread 8x4 outputs.
// MODE 0: conv  (A = x with 3 taps, grouped; epilogue +bias)
// MODE 1: rff   (A = h; B = rff_w[g]; epilogue cos(acc*sg + b)*sqrt(2/256))
// MODE 2: proj  (epilogue +bias)
// MODE 3: final (epilogue +bias, writes d_out)
template<int MODE>
__global__ __launch_bounds__(256) void gemm_tile(
    const float* __restrict__ A, const float* __restrict__ Bw,
    const float* __restrict__ bias, float* __restrict__ C,
    int M, int N, int K)
{
  __shared__ float As[16][132];   // [kk][m], pad 132 for conflict-free access
  __shared__ float Bs[16][64];    // [kk][n]

  const int tid = threadIdx.x;
  const int tx = tid & 15, ty = tid >> 4;
  const int n0 = blockIdx.x * 64;
  const int m0 = blockIdx.y * 128;

  const int ar  = tid >> 1;         // A stage: row 0..127
  const int akc = (tid & 1) * 8;    // A stage: k offset 0/8
  const int bkk = tid >> 4;         // B stage: kk 0..15
  const int bnc = (tid & 15) * 4;   // B stage: n offset
  const int g   = n0 >> 8;          // conv group / rff gamma index
  const int n0m = n0 & 255;

  float acc[8][4];
  #pragma unroll
  for (int i = 0; i < 8; ++i)
    #pragma unroll
    for (int j = 0; j < 4; ++j) acc[i][j] = 0.f;

  for (int k0 = 0; k0 < K; k0 += 16) {
    float4 av[2], bv;
    if constexpr (MODE == 0) {
      // logical A[row][kk], kk = t*256+ci ; value = x[b, s+t-1, g*256+ci] (0 pad)
      const int row = m0 + ar;
      const int bb = row >> 12, s = row & 4095;
      #pragma unroll
      for (int u = 0; u < 2; ++u) {
        const int kk = k0 + akc + u * 4;
        const int t = kk >> 8, ci = kk & 255;
        const int ss = s + t - 1;
        if (ss >= 0 && ss < 4096)
          av[u] = *reinterpret_cast<const float4*>(
              A + ((size_t)(bb * 4096 + ss)) * 1024 + g * 256 + ci);
        else
          av[u] = make_float4(0.f, 0.f, 0.f, 0.f);
      }
    } else {
      const float* ap = A + (size_t)(m0 + ar) * K + k0 + akc;
      av[0] = *reinterpret_cast<const float4*>(ap);
      av[1] = *reinterpret_cast<const float4*>(ap + 4);
    }
    if constexpr (MODE == 1) {
      // rff_w[g][k][m] : g*1024*256 + k*256 + m
      bv = *reinterpret_cast<const float4*>(
          Bw + (size_t)g * 262144 + (size_t)(k0 + bkk) * 256 + n0m + bnc);
    } else {
      bv = *reinterpret_cast<const float4*>(Bw + (size_t)(k0 + bkk) * N + n0 + bnc);
    }

    __syncthreads();   // previous tile's compute done before overwrite
    #pragma unroll
    for (int u = 0; u < 2; ++u) {
      As[akc + u * 4 + 0][ar] = av[u].x;
      As[akc + u * 4 + 1][ar] = av[u].y;
      As[akc + u * 4 + 2][ar] = av[u].z;
      As[akc + u * 4 + 3][ar] = av[u].w;
    }
    *reinterpret_cast<float4*>(&Bs[bkk][bnc]) = bv;
    __syncthreads();

    #pragma unroll
    for (int kk = 0; kk < 16; ++kk) {
      const float4 a0 = *reinterpret_cast<const float4*>(&As[kk][ty * 8]);
      const float4 a1 = *reinterpret_cast<const float4*>(&As[kk][ty * 8 + 4]);
      const float4 b4 = *reinterpret_cast<const float4*>(&Bs[kk][tx * 4]);
      const float am[8] = {a0.x, a0.y, a0.z, a0.w, a1.x, a1.y, a1.z, a1.w};
      const float bn[4] = {b4.x, b4.y, b4.z, b4.w};
      #pragma unroll
      for (int i = 0; i < 8; ++i)
        #pragma unroll
        for (int j = 0; j < 4; ++j)
          acc[i][j] = fmaf(am[i], bn[j], acc[i][j]);
    }
  }

  const int row0 = m0 + ty * 8;
  const int nb = n0 + tx * 4;
  if constexpr (MODE == 1) {
    const float sg = (g == 0) ? 1.0f : ((g == 1) ? 1.41421356237309515f : 2.0f);
    #pragma unroll
    for (int i = 0; i < 8; ++i)
      #pragma unroll
      for (int j = 0; j < 4; ++j) {
        const float v = cosf(acc[i][j] * sg + bias[nb + j]) * 0.08838834764831845f;
        C[(size_t)(row0 + i) * N + nb + j] = v;
      }
  } else {
    #pragma unroll
    for (int i = 0; i < 8; ++i) {
      float4 o;
      o.x = acc[i][0] + bias[nb + 0];
      o.y = acc[i][1] + bias[nb + 1];
      o.z = acc[i][2] + bias[nb + 2];
      o.w = acc[i][3] + bias[nb + 3];
      *reinterpret_cast<float4*>(&C[(size_t)(row0 + i) * N + nb]) = o;
    }
  }
}

// ======================== RoPE (in-place on Q and K) ========================
__global__ __launch_bounds__(256) void rope_kernel(float* __restrict__ Q,
                                                   float* __restrict__ Kb)
{
  const int idx = blockIdx.x * 256 + threadIdx.x;  // 2*4096*16*32
  const int j = idx & 31;
  const int h = (idx >> 5) & 15;
  const int s = (idx >> 9) & 4095;
  const int b = idx >> 21;
  // match np float64-promoted rotary table
  const double inv = pow(10000.0, -(double)j * (1.0 / 32.0));
  const double ang = (double)s * inv;
  double sd, cd;
  sincos(ang, &sd, &cd);
  const float sn = (float)sd, cs = (float)cd;
  const size_t base = ((size_t)(b * 4096 + s)) * 1024 + h * 64 + j;
  const float q0 = Q[base], q1 = Q[base + 32];
  Q[base]      = q0 * cs - q1 * sn;
  Q[base + 32] = q1 * cs + q0 * sn;
  const float k0 = Kb[base], k1 = Kb[base + 32];
  Kb[base]      = k0 * cs - k1 * sn;
  Kb[base + 32] = k1 * cs + k0 * sn;
}

// ======================== Nystrom RBF features ==============================
// out[row, l] = exp(-(|k|^2 + |lm_l|^2 - 2 k.lm_l)/64), rows = (b,s,h), 64 dims
__global__ __launch_bounds__(256) void nystrom_kernel(
    const float* __restrict__ Kb, const float* __restrict__ lm,
    float* __restrict__ kny)
{
  __shared__ float lmT[64][65];
  __shared__ float lnorm[64];
  const int tid = threadIdx.x;
  for (int idx = tid; idx < 4096; idx += 256)
    lmT[idx & 63][idx >> 6] = lm[idx];
  if (tid < 64) {
    float s = 0.f;
    #pragma unroll
    for (int d = 0; d < 64; ++d) { const float v = lm[tid * 64 + d]; s = fmaf(v, v, s); }
    lnorm[tid] = s;
  }
  __syncthreads();
  const int lane = tid & 63;
  const int nw = gridDim.x * 4;
  for (int row = blockIdx.x * 4 + (tid >> 6); row < 131072; row += nw) {
    const float kd = Kb[(size_t)row * 64 + lane];
    float nk = kd * kd;
    #pragma unroll
    for (int o = 32; o > 0; o >>= 1) nk += __shfl_xor(nk, o, 64);
    float dot = 0.f;
    #pragma unroll
    for (int d = 0; d < 64; ++d) dot = fmaf(__shfl(kd, d, 64), lmT[d][lane], dot);
    kny[(size_t)row * 64 + lane] = __expf((2.f * dot - nk - lnorm[lane]) * 0.015625f);
  }
}

// ======================== FAVOR-K: fused kp -> KV/Ksum partials =============
// block = (bh, chunk of 512 rows); thread m owns KV row m (64 f32 regs).
// partial layout: KVp[bid][d][m] (coalesced writes), Ksump[bid][m]
__global__ __launch_bounds__(256) void favor_k_kernel(
    const float* __restrict__ kny, const float* __restrict__ V,
    const float* __restrict__ omega,
    float* __restrict__ KVp, float* __restrict__ Ksump)
{
  const int bid = blockIdx.x;         // 256 = 32 bh * 8 chunks
  const int bh = bid >> 3, chunk = bid & 7;
  const int b = bh >> 4, h = bh & 15;
  const int s0 = chunk * 512;
  const int m = threadIdx.x;

  __shared__ float Ks[16][64];
  __shared__ float Vs[16][64];
  __shared__ float npart[16][16];
  __shared__ float norms[16];

  float accKV[64];
  #pragma unroll
  for (int d = 0; d < 64; ++d) accKV[d] = 0.f;
  float accS = 0.f;

  const int lr = m >> 4, lj = m & 15, lc = lj * 4;

  for (int t0 = 0; t0 < 512; t0 += 16) {
    const size_t gb = ((size_t)(b * 4096 + s0 + t0 + lr)) * 1024 + h * 64 + lc;
    const float4 k4 = *reinterpret_cast<const float4*>(kny + gb);
    const float4 v4 = *reinterpret_cast<const float4*>(V + gb);
    __syncthreads();
    *reinterpret_cast<float4*>(&Ks[lr][lc]) = k4;
    *reinterpret_cast<float4*>(&Vs[lr][lc]) = v4;
    npart[lr][lj] = k4.x * k4.x + k4.y * k4.y + k4.z * k4.z + k4.w * k4.w;
    __syncthreads();
    if (m < 16) {
      float s = 0.f;
      #pragma unroll
      for (int q = 0; q < 16; ++q) s += npart[m][q];
      norms[m] = 0.5f * s;
    }
    __syncthreads();

    float dot[16];
    #pragma unroll
    for (int r = 0; r < 16; ++r) dot[r] = 0.f;
    #pragma unroll
    for (int d4 = 0; d4 < 16; ++d4) {
      const float w0 = omega[(d4 * 4 + 0) * 256 + m];
      const float w1 = omega[(d4 * 4 + 1) * 256 + m];
      const float w2 = omega[(d4 * 4 + 2) * 256 + m];
      const float w3 = omega[(d4 * 4 + 3) * 256 + m];
      #pragma unroll
      for (int r = 0; r < 16; ++r) {
        const float4 kk = *reinterpret_cast<const float4*>(&Ks[r][d4 * 4]);
        float dd = dot[r];
        dd = fmaf(kk.x, w0, dd); dd = fmaf(kk.y, w1, dd);
        dd = fmaf(kk.z, w2, dd); dd = fmaf(kk.w, w3, dd);
        dot[r] = dd;
      }
    }
    #pragma unroll
    for (int r = 0; r < 16; ++r) {
      const float pk = __expf(dot[r] - norms[r]) * 0.0625f;
      accS += pk;
      #pragma unroll
      for (int d4 = 0; d4 < 16; ++d4) {
        const float4 vv = *reinterpret_cast<const float4*>(&Vs[r][d4 * 4]);
        accKV[d4 * 4 + 0] = fmaf(pk, vv.x, accKV[d4 * 4 + 0]);
        accKV[d4 * 4 + 1] = fmaf(pk, vv.y, accKV[d4 * 4 + 1]);
        accKV[d4 * 4 + 2] = fmaf(pk, vv.z, accKV[d4 * 4 + 2]);
        accKV[d4 * 4 + 3] = fmaf(pk, vv.w, accKV[d4 * 4 + 3]);
      }
    }
  }
  const size_t pb = (size_t)bid * 16384;
  #pragma unroll
  for (int d = 0; d < 64; ++d) KVp[pb + d * 256 + m] = accKV[d];
  Ksump[bid * 256 + m] = accS;
}

// ======================== reduce partials ===================================
__global__ __launch_bounds__(256) void reduce_kv_kernel(
    const float* __restrict__ KVp, const float* __restrict__ Ksump,
    float* __restrict__ KV, float* __restrict__ Ksum)
{
  const int idx = blockIdx.x * 256 + threadIdx.x;
  if (idx < 524288) {
    const int bh = idx >> 14, rem = idx & 16383;
    const int d = rem >> 8, m = rem & 255;
    float s = 0.f;
    #pragma unroll
    for (int c = 0; c < 8; ++c)
      s += KVp[((size_t)(bh * 8 + c)) * 16384 + rem];
    KV[((size_t)bh * 256 + m) * 64 + d] = s;
  } else if (idx < 532480) {
    const int j = idx - 524288;
    const int bh = j >> 8, m = j & 255;
    float s = 0.f;
    #pragma unroll
    for (int c = 0; c < 8; ++c)
      s += Ksump[(bh * 8 + c) * 256 + m];
    Ksum[j] = s;
  }
}

// ======================== FAVOR-Q: fused qp -> num/denom -> out =============
__global__ __launch_bounds__(256) void favor_q_kernel(
    const float* __restrict__ Q, const float* __restrict__ omega,
    const float* __restrict__ KV, const float* __restrict__ Ksum,
    float* __restrict__ O)
{
  const int bid = blockIdx.x;           // 512 = 32 bh * 16 chunks of 256 rows
  const int bh = bid >> 4, chunk = bid & 15;
  const int b = bh >> 4, h = bh & 15;
  const int s0 = chunk * 256;
  const int tid = threadIdx.x;

  __shared__ float Qs[16][64];
  __shared__ float qp[16][256];
  __shared__ float npart[16][16];
  __shared__ float norms[16];
  __shared__ float dpart[16][16];
  __shared__ float denom[16];

  const int lr = tid >> 4, lj = tid & 15, lc = lj * 4;
  const int dd = tid & 63, r4 = tid >> 6;

  for (int t0 = 0; t0 < 256; t0 += 16) {
    const size_t gb = ((size_t)(b * 4096 + s0 + t0 + lr)) * 1024 + h * 64 + lc;
    const float4 q4 = *reinterpret_cast<const float4*>(Q + gb);
    __syncthreads();
    *reinterpret_cast<float4*>(&Qs[lr][lc]) = q4;
    npart[lr][lj] = q4.x * q4.x + q4.y * q4.y + q4.z * q4.z + q4.w * q4.w;
    __syncthreads();
    if (tid < 16) {
      float s = 0.f;
      #pragma unroll
      for (int q = 0; q < 16; ++q) s += npart[tid][q];
      norms[tid] = 0.5f * s;
    }
    __syncthreads();
    {
      const int m = tid;
      float dot[16];
      #pragma unroll
      for (int r = 0; r < 16; ++r) dot[r] = 0.f;
      #pragma unroll
      for (int d4 = 0; d4 < 16; ++d4) {
        const float w0 = omega[(d4 * 4 + 0) * 256 + m];
        const float w1 = omega[(d4 * 4 + 1) * 256 + m];
        const float w2 = omega[(d4 * 4 + 2) * 256 + m];
        const float w3 = omega[(d4 * 4 + 3) * 256 + m];
        #pragma unroll
        for (int r = 0; r < 16; ++r) {
          const float4 qq = *reinterpret_cast<const float4*>(&Qs[r][d4 * 4]);
          float dt = dot[r];
          dt = fmaf(qq.x, w0, dt); dt = fmaf(qq.y, w1, dt);
          dt = fmaf(qq.z, w2, dt); dt = fmaf(qq.w, w3, dt);
          dot[r] = dt;
        }
      }
      #pragma unroll
      for (int r = 0; r < 16; ++r)
        qp[r][m] = __expf(dot[r] - norms[r]) * 0.0625f;
    }
    __syncthreads();
    {
      float ds_ = 0.f;
      #pragma unroll
      for (int mm = 0; mm < 16; ++mm)
        ds_ = fmaf(qp[lr][lj * 16 + mm], Ksum[bh * 256 + lj * 16 + mm], ds_);
      dpart[lr][lj] = ds_;
    }
    __syncthreads();
    if (tid < 16) {
      float s = 0.f;
      #pragma unroll
      for (int q = 0; q < 16; ++q) s += dpart[tid][q];
      denom[tid] = s + 1e-6f;
    }
    __syncthreads();

    float a0 = 0.f, a1 = 0.f, a2 = 0.f, a3 = 0.f;
    const float* kvp = KV + (size_t)bh * 16384 + dd;
    for (int mm = 0; mm < 256; ++mm) {
      const float kv = kvp[(size_t)mm * 64];
      a0 = fmaf(qp[r4][mm], kv, a0);
      a1 = fmaf(qp[r4 + 4][mm], kv, a1);
      a2 = fmaf(qp[r4 + 8][mm], kv, a2);
      a3 = fmaf(qp[r4 + 12][mm], kv, a3);
    }
    const size_t ob = ((size_t)(b * 4096 + s0 + t0)) * 1024 + h * 64 + dd;
    O[ob + (size_t)(r4) * 1024]      = a0 / denom[r4];
    O[ob + (size_t)(r4 + 4) * 1024]  = a1 / denom[r4 + 4];
    O[ob + (size_t)(r4 + 8) * 1024]  = a2 / denom[r4 + 8];
    O[ob + (size_t)(r4 + 12) * 1024] = a3 / denom[r4 + 12];
  }
}

// ======================== launcher ==========================================
extern "C" void kernel_launch(void* const* d_in, const int* in_sizes, int n_in,
                              void* d_out, int out_size, void* d_ws, size_t ws_size,
                              hipStream_t stream)
{
  const float* x      = (const float*)d_in[0];
  const float* conv_k = (const float*)d_in[1];
  const float* conv_b = (const float*)d_in[2];
  const float* rff_w  = (const float*)d_in[3];
  const float* rff_b  = (const float*)d_in[4];
  const float* proj_w = (const float*)d_in[5];
  const float* proj_b = (const float*)d_in[6];
  const float* omega  = (const float*)d_in[7];
  const float* lm     = (const float*)d_in[8];
  const float* out_w  = (const float*)d_in[9];
  const float* out_b  = (const float*)d_in[10];

  float* ws  = (float*)d_ws;
  float* A   = ws;                    // 8,388,608  (h buffer, later kny)
  float* Bf  = A + 8388608;           // 6,291,456  (feats)
  float* Qb  = Bf + 6291456;          // 8,388,608
  float* Kb  = Qb + 8388608;          // 8,388,608  (later attn out)
  float* Vb  = Kb + 8388608;          // 8,388,608
  float* KVp = Vb + 8388608;          // 4,194,304
  float* Ksp = KVp + 4194304;         //    65,536
  float* KV  = Ksp + 65536;           //   524,288
  float* Ks  = KV + 524288;           //     8,192

  float* qkv[3] = {Qb, Kb, Vb};
  dim3 blk(256);
  for (int i = 0; i < 3; ++i) {
    gemm_tile<0><<<dim3(16, 64), blk, 0, stream>>>(
        x, conv_k + (size_t)i * 786432, conv_b + i * 1024, A, 8192, 1024, 768);
    gemm_tile<1><<<dim3(12, 64), blk, 0, stream>>>(
        A, rff_w + (size_t)i * 786432, rff_b + i * 768, Bf, 8192, 768, 1024);
    gemm_tile<2><<<dim3(16, 64), blk, 0, stream>>>(
        Bf, proj_w + (size_t)i * 786432, proj_b + i * 1024, qkv[i], 8192, 1024, 768);
  }
  rope_kernel<<<16384, blk, 0, stream>>>(Qb, Kb);
  nystrom_kernel<<<512, blk, 0, stream>>>(Kb, lm, A);
  favor_k_kernel<<<256, blk, 0, stream>>>(A, Vb, omega, KVp, Ksp);
  reduce_kv_kernel<<<2080, blk, 0, stream>>>(KVp, Ksp, KV, Ks);
  favor_q_kernel<<<512, blk, 0, stream>>>(Qb, omega, KV, Ks, Kb);
  gemm_tile<3><<<dim3(16, 64), blk, 0, stream>>>(
      Kb, out_w, out_b, (float*)d_out, 8192, 1024, 1024);
}

// Round 2
// 1658.964 us; speedup vs baseline: 1.6340x; 1.6340x over previous
//
#include <hip/hip_runtime.h>
#include <math.h>

// ---------------------------------------------------------------------------
// B=2, S=4096, C=1024, H=16, Dh=64, G=3, Ms=256, NRF=256, L=64
// Round 2: bf16 MFMA GEMMs (split hi/lo for conv+rff), rope table,
//          favor_q KV LDS staging. favor_k/nystrom unchanged f32.
// ---------------------------------------------------------------------------

using f32x4 = __attribute__((ext_vector_type(4))) float;
using s16x8 = __attribute__((ext_vector_type(8))) short;

__device__ __forceinline__ unsigned short f2bf(float x) {
  unsigned u = __float_as_uint(x);
  unsigned r = u + 0x7fffu + ((u >> 16) & 1u);
  return (unsigned short)(r >> 16);
}
__device__ __forceinline__ float bf2f(unsigned short h) {
  return __uint_as_float(((unsigned)h) << 16);
}

// ======================== weight transpose + convert ========================
// in [K][N] f32 -> out [N][K] bf16 (hi, and lo if WM<=1)
template<int WM>  // 0 conv(3i, split) 1 rff(9 z=i*3+g, split) 2 proj(3i) 3 out_w
__global__ __launch_bounds__(256) void wconv_kernel(
    const float* __restrict__ in0, unsigned short* __restrict__ ohi,
    unsigned short* __restrict__ olo)
{
  int K, N;
  const float* in;
  unsigned short *oh, *ol = nullptr;
  const int z = blockIdx.z;
  if constexpr (WM == 0) {
    K = 768; N = 1024;
    in = in0 + (size_t)z * 786432;
    oh = ohi + (size_t)z * 786432; ol = olo + (size_t)z * 786432;
  } else if constexpr (WM == 1) {
    K = 1024; N = 256;
    const int i = z / 3, g = z % 3;
    in = in0 + (size_t)i * 786432 + (size_t)g * 262144;
    oh = ohi + (size_t)i * 786432 + (size_t)g * 262144;
    ol = olo + (size_t)i * 786432 + (size_t)g * 262144;
  } else if constexpr (WM == 2) {
    K = 768; N = 1024;
    in = in0 + (size_t)z * 786432; oh = ohi + (size_t)z * 786432;
  } else {
    K = 1024; N = 1024; in = in0; oh = ohi;
  }
  const int k0 = blockIdx.x * 64, n0 = blockIdx.y * 64;
  __shared__ float t[64][65];
  const int tid = threadIdx.x, tn = tid & 63, tr = tid >> 6;
  #pragma unroll 4
  for (int p = 0; p < 16; ++p) {
    const int kk = p * 4 + tr;
    t[kk][tn] = in[(size_t)(k0 + kk) * N + n0 + tn];
  }
  __syncthreads();
  #pragma unroll 4
  for (int p = 0; p < 16; ++p) {
    const int nn = p * 4 + tr;
    const float v = t[tn][nn];
    const unsigned short hi = f2bf(v);
    oh[(size_t)(n0 + nn) * K + k0 + tn] = hi;
    if constexpr (WM <= 1)
      ol[(size_t)(n0 + nn) * K + k0 + tn] = f2bf(v - bf2f(hi));
  }
}

// ======================== MFMA GEMM =========================================
// 128x128 tile, BK=32, 256 threads (2x2 waves of 64x64), 16x16x32 bf16 MFMA.
// MODE 0 conv (split, im2col from x, +bias -> h f32)
// MODE 1 rff  (split, A=h f32, cos epilogue -> feats bf16)
// MODE 2 proj (plain, A=feats bf16, +bias -> f32)
// MODE 3 final(plain, A=O f32, +bias -> f32)
template<int MODE>
__global__ __launch_bounds__(256, 2) void gemm_mfma(
    const void* __restrict__ Asrc,
    const unsigned short* __restrict__ Bhig,
    const unsigned short* __restrict__ Blog,
    const float* __restrict__ bias,
    float* __restrict__ Cf, unsigned short* __restrict__ Cb,
    int M, int N, int K)
{
  constexpr bool SPLIT = (MODE <= 1);
  __shared__ alignas(16) char smem[SPLIT ? 32768 : 16384];
  char* const sAhi = smem;
  char* const sBhi = smem + (SPLIT ? 16384 : 8192);
  char* const sAlo = smem + 8192;    // valid only if SPLIT
  char* const sBlo = smem + 24576;   // valid only if SPLIT

  const int tid = threadIdx.x;
  const int n0 = blockIdx.x * 128;
  const int m0 = blockIdx.y * 128;

  // staging mapping: thread -> (row, 16-elem half of BK)
  const int sr = tid >> 1;
  const int kh = (tid & 1) * 16;
  const int sw = ((sr >> 1) & 3) << 4;
  const int c0 = kh >> 3;                       // chunk 0 or 2
  const int db0 = sr * 64 + ((c0 * 16) ^ sw);
  const int db1 = sr * 64 + (((c0 + 1) * 16) ^ sw);

  const int lane = tid & 63, wid = tid >> 6;
  const int wr = wid >> 1, wc = wid & 1;
  const int fr = lane & 15, kc = lane >> 4;
  const int fsw = ((fr >> 1) & 3) << 4;

  f32x4 acc[4][4];
  #pragma unroll
  for (int i = 0; i < 4; ++i)
    #pragma unroll
    for (int j = 0; j < 4; ++j) acc[i][j] = f32x4{0.f, 0.f, 0.f, 0.f};

  for (int k0 = 0; k0 < K; k0 += 32) {
    s16x8 ah0, ah1, al0, al1, bh0, bh1, bl0, bl1;
    // ---- A global -> regs (+convert) ----
    if constexpr (MODE == 2) {
      const unsigned short* ap =
          (const unsigned short*)Asrc + (size_t)(m0 + sr) * K + k0 + kh;
      ah0 = *(const s16x8*)ap; ah1 = *(const s16x8*)(ap + 8);
    } else {
      float v[16];
      bool valid = true;
      const float* af;
      if constexpr (MODE == 0) {
        const int grow = m0 + sr;
        const int bb = grow >> 12, s = grow & 4095;
        const int t = k0 >> 8;
        const int ss = s + t - 1;
        valid = ((unsigned)ss < 4096u);
        const int ci = (k0 & 255) + kh;
        af = (const float*)Asrc +
             ((size_t)(bb * 4096 + (valid ? ss : 0))) * 1024 + (n0 >> 8) * 256 + ci;
      } else {
        af = (const float*)Asrc + (size_t)(m0 + sr) * K + k0 + kh;
      }
      if (valid) {
        const float4 f0 = ((const float4*)af)[0];
        const float4 f1 = ((const float4*)af)[1];
        const float4 f2 = ((const float4*)af)[2];
        const float4 f3 = ((const float4*)af)[3];
        v[0]=f0.x; v[1]=f0.y; v[2]=f0.z; v[3]=f0.w;
        v[4]=f1.x; v[5]=f1.y; v[6]=f1.z; v[7]=f1.w;
        v[8]=f2.x; v[9]=f2.y; v[10]=f2.z; v[11]=f2.w;
        v[12]=f3.x; v[13]=f3.y; v[14]=f3.z; v[15]=f3.w;
      } else {
        #pragma unroll
        for (int u = 0; u < 16; ++u) v[u] = 0.f;
      }
      #pragma unroll
      for (int u = 0; u < 8; ++u) {
        const unsigned short h0 = f2bf(v[u]);
        const unsigned short h1 = f2bf(v[u + 8]);
        ah0[u] = (short)h0; ah1[u] = (short)h1;
        if constexpr (SPLIT) {
          al0[u] = (short)f2bf(v[u] - bf2f(h0));
          al1[u] = (short)f2bf(v[u + 8] - bf2f(h1));
        }
      }
    }
    // ---- B global -> regs ----
    {
      const unsigned short* bp = Bhig + (size_t)(n0 + sr) * K + k0 + kh;
      bh0 = *(const s16x8*)bp; bh1 = *(const s16x8*)(bp + 8);
      if constexpr (SPLIT) {
        const unsigned short* bq = Blog + (size_t)(n0 + sr) * K + k0 + kh;
        bl0 = *(const s16x8*)bq; bl1 = *(const s16x8*)(bq + 8);
      }
    }
    __syncthreads();   // prior tile reads done
    *(s16x8*)(sAhi + db0) = ah0; *(s16x8*)(sAhi + db1) = ah1;
    *(s16x8*)(sBhi + db0) = bh0; *(s16x8*)(sBhi + db1) = bh1;
    if constexpr (SPLIT) {
      *(s16x8*)(sAlo + db0) = al0; *(s16x8*)(sAlo + db1) = al1;
      *(s16x8*)(sBlo + db0) = bl0; *(s16x8*)(sBlo + db1) = bl1;
    }
    __syncthreads();

    s16x8 Af[4], Al[4], Bf[4], Bl[4];
    #pragma unroll
    for (int i = 0; i < 4; ++i) {
      const int off = (wr * 64 + i * 16 + fr) * 64 + ((kc * 16) ^ fsw);
      Af[i] = *(const s16x8*)(sAhi + off);
      if constexpr (SPLIT) Al[i] = *(const s16x8*)(sAlo + off);
    }
    #pragma unroll
    for (int j = 0; j < 4; ++j) {
      const int off = (wc * 64 + j * 16 + fr) * 64 + ((kc * 16) ^ fsw);
      Bf[j] = *(const s16x8*)(sBhi + off);
      if constexpr (SPLIT) Bl[j] = *(const s16x8*)(sBlo + off);
    }
    #pragma unroll
    for (int i = 0; i < 4; ++i)
      #pragma unroll
      for (int j = 0; j < 4; ++j) {
        acc[i][j] = __builtin_amdgcn_mfma_f32_16x16x32_bf16(Af[i], Bf[j], acc[i][j], 0, 0, 0);
        if constexpr (SPLIT) {
          acc[i][j] = __builtin_amdgcn_mfma_f32_16x16x32_bf16(Af[i], Bl[j], acc[i][j], 0, 0, 0);
          acc[i][j] = __builtin_amdgcn_mfma_f32_16x16x32_bf16(Al[i], Bf[j], acc[i][j], 0, 0, 0);
        }
      }
  }

  // ---- epilogue ----
  #pragma unroll
  for (int i = 0; i < 4; ++i)
    #pragma unroll
    for (int j = 0; j < 4; ++j) {
      const int col = n0 + wc * 64 + j * 16 + fr;
      #pragma unroll
      for (int rr = 0; rr < 4; ++rr) {
        const int row = m0 + wr * 64 + i * 16 + kc * 4 + rr;
        const float v = acc[i][j][rr];
        if constexpr (MODE == 1) {
          const int g = col >> 8;
          const float sg = (g == 0) ? 1.0f : ((g == 1) ? 1.41421356237309515f : 2.0f);
          const float z = cosf(v * sg + bias[col]) * 0.08838834764831845f;
          Cb[(size_t)row * N + col] = f2bf(z);
        } else {
          Cf[(size_t)row * N + col] = v + bias[col];
        }
      }
    }
}

// ======================== RoPE table + apply ================================
__global__ __launch_bounds__(256) void rope_table_kernel(float2* __restrict__ tab)
{
  const int idx = blockIdx.x * 256 + threadIdx.x;  // 4096*32
  const int j = idx & 31, s = idx >> 5;
  const double inv = pow(10000.0, -(double)j * (1.0 / 32.0));
  double sd, cd;
  sincos((double)s * inv, &sd, &cd);
  tab[idx] = make_float2((float)cd, (float)sd);
}

__global__ __launch_bounds__(256) void rope_apply_kernel(
    const float2* __restrict__ tab, float* __restrict__ Q, float* __restrict__ Kb)
{
  const int idx = blockIdx.x * 256 + threadIdx.x;  // 2*4096*16*32
  const int j = idx & 31;
  const int h = (idx >> 5) & 15;
  const int s = (idx >> 9) & 4095;
  const int b = idx >> 21;
  const float2 cs = tab[(s << 5) | j];
  const float snv = cs.y, csv = cs.x;
  const size_t base = ((size_t)(b * 4096 + s)) * 1024 + h * 64 + j;
  const float q0 = Q[base], q1 = Q[base + 32];
  Q[base]      = q0 * csv - q1 * snv;
  Q[base + 32] = q1 * csv + q0 * snv;
  const float k0 = Kb[base], k1 = Kb[base + 32];
  Kb[base]      = k0 * csv - k1 * snv;
  Kb[base + 32] = k1 * csv + k0 * snv;
}

// ======================== Nystrom RBF features ==============================
__global__ __launch_bounds__(256) void nystrom_kernel(
    const float* __restrict__ Kb, const float* __restrict__ lm,
    float* __restrict__ kny)
{
  __shared__ float lmT[64][65];
  __shared__ float lnorm[64];
  const int tid = threadIdx.x;
  for (int idx = tid; idx < 4096; idx += 256)
    lmT[idx & 63][idx >> 6] = lm[idx];
  if (tid < 64) {
    float s = 0.f;
    #pragma unroll
    for (int d = 0; d < 64; ++d) { const float v = lm[tid * 64 + d]; s = fmaf(v, v, s); }
    lnorm[tid] = s;
  }
  __syncthreads();
  const int lane = tid & 63;
  const int nw = gridDim.x * 4;
  for (int row = blockIdx.x * 4 + (tid >> 6); row < 131072; row += nw) {
    const float kd = Kb[(size_t)row * 64 + lane];
    float nk = kd * kd;
    #pragma unroll
    for (int o = 32; o > 0; o >>= 1) nk += __shfl_xor(nk, o, 64);
    float dot = 0.f;
    #pragma unroll
    for (int d = 0; d < 64; ++d) dot = fmaf(__shfl(kd, d, 64), lmT[d][lane], dot);
    kny[(size_t)row * 64 + lane] = __expf((2.f * dot - nk - lnorm[lane]) * 0.015625f);
  }
}

// ======================== FAVOR-K ===========================================
__global__ __launch_bounds__(256) void favor_k_kernel(
    const float* __restrict__ kny, const float* __restrict__ V,
    const float* __restrict__ omega,
    float* __restrict__ KVp, float* __restrict__ Ksump)
{
  const int bid = blockIdx.x;         // 256 = 32 bh * 8 chunks
  const int bh = bid >> 3, chunk = bid & 7;
  const int b = bh >> 4, h = bh & 15;
  const int s0 = chunk * 512;
  const int m = threadIdx.x;

  __shared__ float Ks[16][64];
  __shared__ float Vs[16][64];
  __shared__ float npart[16][16];
  __shared__ float norms[16];

  float accKV[64];
  #pragma unroll
  for (int d = 0; d < 64; ++d) accKV[d] = 0.f;
  float accS = 0.f;

  const int lr = m >> 4, lj = m & 15, lc = lj * 4;

  for (int t0 = 0; t0 < 512; t0 += 16) {
    const size_t gb = ((size_t)(b * 4096 + s0 + t0 + lr)) * 1024 + h * 64 + lc;
    const float4 k4 = *reinterpret_cast<const float4*>(kny + gb);
    const float4 v4 = *reinterpret_cast<const float4*>(V + gb);
    __syncthreads();
    *reinterpret_cast<float4*>(&Ks[lr][lc]) = k4;
    *reinterpret_cast<float4*>(&Vs[lr][lc]) = v4;
    npart[lr][lj] = k4.x * k4.x + k4.y * k4.y + k4.z * k4.z + k4.w * k4.w;
    __syncthreads();
    if (m < 16) {
      float s = 0.f;
      #pragma unroll
      for (int q = 0; q < 16; ++q) s += npart[m][q];
      norms[m] = 0.5f * s;
    }
    __syncthreads();

    float dot[16];
    #pragma unroll
    for (int r = 0; r < 16; ++r) dot[r] = 0.f;
    #pragma unroll
    for (int d4 = 0; d4 < 16; ++d4) {
      const float w0 = omega[(d4 * 4 + 0) * 256 + m];
      const float w1 = omega[(d4 * 4 + 1) * 256 + m];
      const float w2 = omega[(d4 * 4 + 2) * 256 + m];
      const float w3 = omega[(d4 * 4 + 3) * 256 + m];
      #pragma unroll
      for (int r = 0; r < 16; ++r) {
        const float4 kk = *reinterpret_cast<const float4*>(&Ks[r][d4 * 4]);
        float dd = dot[r];
        dd = fmaf(kk.x, w0, dd); dd = fmaf(kk.y, w1, dd);
        dd = fmaf(kk.z, w2, dd); dd = fmaf(kk.w, w3, dd);
        dot[r] = dd;
      }
    }
    #pragma unroll
    for (int r = 0; r < 16; ++r) {
      const float pk = __expf(dot[r] - norms[r]) * 0.0625f;
      accS += pk;
      #pragma unroll
      for (int d4 = 0; d4 < 16; ++d4) {
        const float4 vv = *reinterpret_cast<const float4*>(&Vs[r][d4 * 4]);
        accKV[d4 * 4 + 0] = fmaf(pk, vv.x, accKV[d4 * 4 + 0]);
        accKV[d4 * 4 + 1] = fmaf(pk, vv.y, accKV[d4 * 4 + 1]);
        accKV[d4 * 4 + 2] = fmaf(pk, vv.z, accKV[d4 * 4 + 2]);
        accKV[d4 * 4 + 3] = fmaf(pk, vv.w, accKV[d4 * 4 + 3]);
      }
    }
  }
  const size_t pb = (size_t)bid * 16384;
  #pragma unroll
  for (int d = 0; d < 64; ++d) KVp[pb + d * 256 + m] = accKV[d];
  Ksump[bid * 256 + m] = accS;
}

// ======================== reduce partials ===================================
__global__ __launch_bounds__(256) void reduce_kv_kernel(
    const float* __restrict__ KVp, const float* __restrict__ Ksump,
    float* __restrict__ KV, float* __restrict__ Ksum)
{
  const int idx = blockIdx.x * 256 + threadIdx.x;
  if (idx < 524288) {
    const int bh = idx >> 14, rem = idx & 16383;
    const int d = rem >> 8, m = rem & 255;
    float s = 0.f;
    #pragma unroll
    for (int c = 0; c < 8; ++c)
      s += KVp[((size_t)(bh * 8 + c)) * 16384 + rem];
    KV[((size_t)bh * 256 + m) * 64 + d] = s;
  } else if (idx < 532480) {
    const int j = idx - 524288;
    const int bh = j >> 8, m = j & 255;
    float s = 0.f;
    #pragma unroll
    for (int c = 0; c < 8; ++c)
      s += Ksump[(bh * 8 + c) * 256 + m];
    Ksum[j] = s;
  }
}

// ======================== FAVOR-Q (KV LDS-staged) ===========================
__global__ __launch_bounds__(256) void favor_q_kernel(
    const float* __restrict__ Q, const float* __restrict__ omega,
    const float* __restrict__ KV, const float* __restrict__ Ksum,
    float* __restrict__ O)
{
  const int bid = blockIdx.x;           // 512 = 32 bh * 16 chunks of 256 rows
  const int bh = bid >> 4, chunk = bid & 15;
  const int b = bh >> 4, h = bh & 15;
  const int s0 = chunk * 256;
  const int tid = threadIdx.x;

  __shared__ float Qs[16][64];
  __shared__ float qp[16][256];
  __shared__ float kvs[64][64];
  __shared__ float npart[16][16];
  __shared__ float norms[16];
  __shared__ float dpart[16][16];
  __shared__ float denom[16];

  const int lr = tid >> 4, lj = tid & 15, lc = lj * 4;
  const int dd = tid & 63, r4 = tid >> 6;

  for (int t0 = 0; t0 < 256; t0 += 16) {
    const size_t gb = ((size_t)(b * 4096 + s0 + t0 + lr)) * 1024 + h * 64 + lc;
    const float4 q4 = *reinterpret_cast<const float4*>(Q + gb);
    __syncthreads();
    *reinterpret_cast<float4*>(&Qs[lr][lc]) = q4;
    npart[lr][lj] = q4.x * q4.x + q4.y * q4.y + q4.z * q4.z + q4.w * q4.w;
    __syncthreads();
    if (tid < 16) {
      float s = 0.f;
      #pragma unroll
      for (int q = 0; q < 16; ++q) s += npart[tid][q];
      norms[tid] = 0.5f * s;
    }
    __syncthreads();
    {
      const int m = tid;
      float dot[16];
      #pragma unroll
      for (int r = 0; r < 16; ++r) dot[r] = 0.f;
      #pragma unroll
      for (int d4 = 0; d4 < 16; ++d4) {
        const float w0 = omega[(d4 * 4 + 0) * 256 + m];
        const float w1 = omega[(d4 * 4 + 1) * 256 + m];
        const float w2 = omega[(d4 * 4 + 2) * 256 + m];
        const float w3 = omega[(d4 * 4 + 3) * 256 + m];
        #pragma unroll
        for (int r = 0; r < 16; ++r) {
          const float4 qq = *reinterpret_cast<const float4*>(&Qs[r][d4 * 4]);
          float dt = dot[r];
          dt = fmaf(qq.x, w0, dt); dt = fmaf(qq.y, w1, dt);
          dt = fmaf(qq.z, w2, dt); dt = fmaf(qq.w, w3, dt);
          dot[r] = dt;
        }
      }
      #pragma unroll
      for (int r = 0; r < 16; ++r)
        qp[r][m] = __expf(dot[r] - norms[r]) * 0.0625f;
    }
    __syncthreads();
    {
      float ds_ = 0.f;
      #pragma unroll
      for (int mm = 0; mm < 16; ++mm)
        ds_ = fmaf(qp[lr][lj * 16 + mm], Ksum[bh * 256 + lj * 16 + mm], ds_);
      dpart[lr][lj] = ds_;
    }
    __syncthreads();
    if (tid < 16) {
      float s = 0.f;
      #pragma unroll
      for (int q = 0; q < 16; ++q) s += dpart[tid][q];
      denom[tid] = s + 1e-6f;
    }
    __syncthreads();

    float a0 = 0.f, a1 = 0.f, a2 = 0.f, a3 = 0.f;
    for (int cm = 0; cm < 4; ++cm) {
      __syncthreads();
      #pragma unroll 4
      for (int p = 0; p < 16; ++p)
        kvs[p * 4 + r4][dd] =
            KV[((size_t)bh * 256 + cm * 64 + p * 4 + r4) * 64 + dd];
      __syncthreads();
      #pragma unroll 8
      for (int mm = 0; mm < 64; ++mm) {
        const float kv = kvs[mm][dd];
        a0 = fmaf(qp[r4][cm * 64 + mm], kv, a0);
        a1 = fmaf(qp[r4 + 4][cm * 64 + mm], kv, a1);
        a2 = fmaf(qp[r4 + 8][cm * 64 + mm], kv, a2);
        a3 = fmaf(qp[r4 + 12][cm * 64 + mm], kv, a3);
      }
    }
    const size_t ob = ((size_t)(b * 4096 + s0 + t0)) * 1024 + h * 64 + dd;
    O[ob + (size_t)(r4) * 1024]      = a0 / denom[r4];
    O[ob + (size_t)(r4 + 4) * 1024]  = a1 / denom[r4 + 4];
    O[ob + (size_t)(r4 + 8) * 1024]  = a2 / denom[r4 + 8];
    O[ob + (size_t)(r4 + 12) * 1024] = a3 / denom[r4 + 12];
  }
}

// ======================== launcher ==========================================
extern "C" void kernel_launch(void* const* d_in, const int* in_sizes, int n_in,
                              void* d_out, int out_size, void* d_ws, size_t ws_size,
                              hipStream_t stream)
{
  const float* x      = (const float*)d_in[0];
  const float* conv_k = (const float*)d_in[1];
  const float* conv_b = (const float*)d_in[2];
  const float* rff_w  = (const float*)d_in[3];
  const float* rff_b  = (const float*)d_in[4];
  const float* proj_w = (const float*)d_in[5];
  const float* proj_b = (const float*)d_in[6];
  const float* omega  = (const float*)d_in[7];
  const float* lm     = (const float*)d_in[8];
  const float* out_w  = (const float*)d_in[9];
  const float* out_b  = (const float*)d_in[10];

  char* wsb = (char*)d_ws;
  size_t o = 0;
  auto alloc = [&](size_t bytes) {
    char* p = wsb + o;
    o = (o + bytes + 255) & ~(size_t)255;
    return p;
  };
  unsigned short* Wc_hi = (unsigned short*)alloc(4718592);
  unsigned short* Wc_lo = (unsigned short*)alloc(4718592);
  unsigned short* Wr_hi = (unsigned short*)alloc(4718592);
  unsigned short* Wr_lo = (unsigned short*)alloc(4718592);
  unsigned short* Wp    = (unsigned short*)alloc(4718592);
  unsigned short* Wo    = (unsigned short*)alloc(2097152);
  float* hbuf  = (float*)alloc(33554432);          // h f32; later kny
  unsigned short* feats = (unsigned short*)alloc(12582912);
  float* Qb = (float*)alloc(33554432);
  float* Kb = (float*)alloc(33554432);
  float* Vb = (float*)alloc(33554432);
  float2* tab = (float2*)alloc(1048576);
  float* KVp = (float*)alloc(16777216);
  float* Ksp = (float*)alloc(262144);
  float* KV  = (float*)alloc(2097152);
  float* Ks  = (float*)alloc(32768);
  float* O   = (float*)alloc(33554432);

  dim3 blk(256);
  // weight conversion (transpose + bf16 hi/lo)
  wconv_kernel<0><<<dim3(12, 16, 3), blk, 0, stream>>>(conv_k, Wc_hi, Wc_lo);
  wconv_kernel<1><<<dim3(16, 4, 9),  blk, 0, stream>>>(rff_w, Wr_hi, Wr_lo);
  wconv_kernel<2><<<dim3(12, 16, 3), blk, 0, stream>>>(proj_w, Wp, nullptr);
  wconv_kernel<3><<<dim3(16, 16, 1), blk, 0, stream>>>(out_w, Wo, nullptr);
  rope_table_kernel<<<512, blk, 0, stream>>>(tab);

  float* qkv[3] = {Qb, Kb, Vb};
  for (int i = 0; i < 3; ++i) {
    gemm_mfma<0><<<dim3(8, 64), blk, 0, stream>>>(
        x, Wc_hi + (size_t)i * 786432, Wc_lo + (size_t)i * 786432,
        conv_b + i * 1024, hbuf, nullptr, 8192, 1024, 768);
    gemm_mfma<1><<<dim3(6, 64), blk, 0, stream>>>(
        hbuf, Wr_hi + (size_t)i * 786432, Wr_lo + (size_t)i * 786432,
        rff_b + i * 768, nullptr, feats, 8192, 768, 1024);
    gemm_mfma<2><<<dim3(8, 64), blk, 0, stream>>>(
        feats, Wp + (size_t)i * 786432, nullptr,
        proj_b + i * 1024, qkv[i], nullptr, 8192, 1024, 768);
  }
  rope_apply_kernel<<<16384, blk, 0, stream>>>(tab, Qb, Kb);
  nystrom_kernel<<<512, blk, 0, stream>>>(Kb, lm, hbuf);
  favor_k_kernel<<<256, blk, 0, stream>>>(hbuf, Vb, omega, KVp, Ksp);
  reduce_kv_kernel<<<2080, blk, 0, stream>>>(KVp, Ksp, KV, Ks);
  favor_q_kernel<<<512, blk, 0, stream>>>(Qb, omega, KV, Ks, O);
  gemm_mfma<3><<<dim3(8, 64), blk, 0, stream>>>(
      O, Wo, nullptr, out_b, (float*)d_out, nullptr, 8192, 1024, 1024);
}

// Round 3
// 1203.401 us; speedup vs baseline: 2.2526x; 1.3786x over previous
//
#include <hip/hip_runtime.h>
#include <math.h>

// ---------------------------------------------------------------------------
// B=2, S=4096, C=1024, H=16, Dh=64, G=3, Ms=256, NRF=256, L=64
// Round 3: MFMA FAVOR stage (favor_k / favor_q), VT/omegaT/KVXT prep,
//          O written bf16 so final GEMM is plain-bf16 path.
// ---------------------------------------------------------------------------

using f32x4 = __attribute__((ext_vector_type(4))) float;
using s16x8 = __attribute__((ext_vector_type(8))) short;

__device__ __forceinline__ unsigned short f2bf(float x) {
  unsigned u = __float_as_uint(x);
  unsigned r = u + 0x7fffu + ((u >> 16) & 1u);
  return (unsigned short)(r >> 16);
}
__device__ __forceinline__ float bf2f(unsigned short h) {
  return __uint_as_float(((unsigned)h) << 16);
}

// ======================== weight transpose + convert ========================
template<int WM>  // 0 conv(3i, split) 1 rff(9 z=i*3+g, split) 2 proj(3i) 3 out_w
__global__ __launch_bounds__(256) void wconv_kernel(
    const float* __restrict__ in0, unsigned short* __restrict__ ohi,
    unsigned short* __restrict__ olo)
{
  int K, N;
  const float* in;
  unsigned short *oh, *ol = nullptr;
  const int z = blockIdx.z;
  if constexpr (WM == 0) {
    K = 768; N = 1024;
    in = in0 + (size_t)z * 786432;
    oh = ohi + (size_t)z * 786432; ol = olo + (size_t)z * 786432;
  } else if constexpr (WM == 1) {
    K = 1024; N = 256;
    const int i = z / 3, g = z % 3;
    in = in0 + (size_t)i * 786432 + (size_t)g * 262144;
    oh = ohi + (size_t)i * 786432 + (size_t)g * 262144;
    ol = olo + (size_t)i * 786432 + (size_t)g * 262144;
  } else if constexpr (WM == 2) {
    K = 768; N = 1024;
    in = in0 + (size_t)z * 786432; oh = ohi + (size_t)z * 786432;
  } else {
    K = 1024; N = 1024; in = in0; oh = ohi;
  }
  const int k0 = blockIdx.x * 64, n0 = blockIdx.y * 64;
  __shared__ float t[64][65];
  const int tid = threadIdx.x, tn = tid & 63, tr = tid >> 6;
  #pragma unroll 4
  for (int p = 0; p < 16; ++p) {
    const int kk = p * 4 + tr;
    t[kk][tn] = in[(size_t)(k0 + kk) * N + n0 + tn];
  }
  __syncthreads();
  #pragma unroll 4
  for (int p = 0; p < 16; ++p) {
    const int nn = p * 4 + tr;
    const float v = t[tn][nn];
    const unsigned short hi = f2bf(v);
    oh[(size_t)(n0 + nn) * K + k0 + tn] = hi;
    if constexpr (WM <= 1)
      ol[(size_t)(n0 + nn) * K + k0 + tn] = f2bf(v - bf2f(hi));
  }
}

// omega [64][256] f32 -> omegaT [256][64] bf16 hi/lo
__global__ __launch_bounds__(256) void omega_prep_kernel(
    const float* __restrict__ omega, unsigned short* __restrict__ oThi,
    unsigned short* __restrict__ oTlo)
{
  const int idx = blockIdx.x * 256 + threadIdx.x;  // 16384
  const int m = idx >> 6, d = idx & 63;
  const float v = omega[d * 256 + m];
  const unsigned short hi = f2bf(v);
  oThi[idx] = hi;
  oTlo[idx] = f2bf(v - bf2f(hi));
}

// V [8192][1024] f32 -> VT[bh][80][4096] bf16 (rows 0..63 = V^T per head)
__global__ __launch_bounds__(256) void vt_kernel(
    const float* __restrict__ V, unsigned short* __restrict__ VT)
{
  const int bh = blockIdx.x, sb = blockIdx.y;
  const int b = bh >> 4, h = bh & 15;
  __shared__ float t[64][65];
  const int tid = threadIdx.x, tn = tid & 63, tr = tid >> 6;
  #pragma unroll 4
  for (int p = 0; p < 16; ++p)
    t[p * 4 + tr][tn] =
        V[(size_t)(b * 4096 + sb * 64 + p * 4 + tr) * 1024 + h * 64 + tn];
  __syncthreads();
  #pragma unroll 4
  for (int p = 0; p < 16; ++p)
    VT[((size_t)bh * 80 + p * 4 + tr) * 4096 + sb * 64 + tn] =
        f2bf(t[tn][p * 4 + tr]);
}

// VT rows 64..79: row 64 = 1.0 (ksum column), rows 65..79 = 0
__global__ __launch_bounds__(256) void vt_fill_kernel(unsigned short* __restrict__ VT)
{
  const int idx = blockIdx.x * 256 + threadIdx.x;  // 32*16*4096
  const int s = idx & 4095, rr = (idx >> 12) & 15, bh = idx >> 16;
  VT[((size_t)bh * 80 + 64 + rr) * 4096 + s] = (rr == 0) ? 0x3F80 : 0;
}

// ======================== MFMA GEMM (unchanged from r2) =====================
template<int MODE>
__global__ __launch_bounds__(256, 2) void gemm_mfma(
    const void* __restrict__ Asrc,
    const unsigned short* __restrict__ Bhig,
    const unsigned short* __restrict__ Blog,
    const float* __restrict__ bias,
    float* __restrict__ Cf, unsigned short* __restrict__ Cb,
    int M, int N, int K)
{
  constexpr bool SPLIT = (MODE <= 1);
  __shared__ alignas(16) char smem[SPLIT ? 32768 : 16384];
  char* const sAhi = smem;
  char* const sBhi = smem + (SPLIT ? 16384 : 8192);
  char* const sAlo = smem + 8192;
  char* const sBlo = smem + 24576;

  const int tid = threadIdx.x;
  const int n0 = blockIdx.x * 128;
  const int m0 = blockIdx.y * 128;

  const int sr = tid >> 1;
  const int kh = (tid & 1) * 16;
  const int sw = ((sr >> 1) & 3) << 4;
  const int c0 = kh >> 3;
  const int db0 = sr * 64 + ((c0 * 16) ^ sw);
  const int db1 = sr * 64 + (((c0 + 1) * 16) ^ sw);

  const int lane = tid & 63, wid = tid >> 6;
  const int wr = wid >> 1, wc = wid & 1;
  const int fr = lane & 15, kc = lane >> 4;
  const int fsw = ((fr >> 1) & 3) << 4;

  f32x4 acc[4][4];
  #pragma unroll
  for (int i = 0; i < 4; ++i)
    #pragma unroll
    for (int j = 0; j < 4; ++j) acc[i][j] = f32x4{0.f, 0.f, 0.f, 0.f};

  for (int k0 = 0; k0 < K; k0 += 32) {
    s16x8 ah0, ah1, al0, al1, bh0, bh1, bl0, bl1;
    if constexpr (MODE == 2) {
      const unsigned short* ap =
          (const unsigned short*)Asrc + (size_t)(m0 + sr) * K + k0 + kh;
      ah0 = *(const s16x8*)ap; ah1 = *(const s16x8*)(ap + 8);
    } else {
      float v[16];
      bool valid = true;
      const float* af;
      if constexpr (MODE == 0) {
        const int grow = m0 + sr;
        const int bb = grow >> 12, s = grow & 4095;
        const int t = k0 >> 8;
        const int ss = s + t - 1;
        valid = ((unsigned)ss < 4096u);
        const int ci = (k0 & 255) + kh;
        af = (const float*)Asrc +
             ((size_t)(bb * 4096 + (valid ? ss : 0))) * 1024 + (n0 >> 8) * 256 + ci;
      } else {
        af = (const float*)Asrc + (size_t)(m0 + sr) * K + k0 + kh;
      }
      if (valid) {
        const float4 f0 = ((const float4*)af)[0];
        const float4 f1 = ((const float4*)af)[1];
        const float4 f2 = ((const float4*)af)[2];
        const float4 f3 = ((const float4*)af)[3];
        v[0]=f0.x; v[1]=f0.y; v[2]=f0.z; v[3]=f0.w;
        v[4]=f1.x; v[5]=f1.y; v[6]=f1.z; v[7]=f1.w;
        v[8]=f2.x; v[9]=f2.y; v[10]=f2.z; v[11]=f2.w;
        v[12]=f3.x; v[13]=f3.y; v[14]=f3.z; v[15]=f3.w;
      } else {
        #pragma unroll
        for (int u = 0; u < 16; ++u) v[u] = 0.f;
      }
      #pragma unroll
      for (int u = 0; u < 8; ++u) {
        const unsigned short h0 = f2bf(v[u]);
        const unsigned short h1 = f2bf(v[u + 8]);
        ah0[u] = (short)h0; ah1[u] = (short)h1;
        if constexpr (SPLIT) {
          al0[u] = (short)f2bf(v[u] - bf2f(h0));
          al1[u] = (short)f2bf(v[u + 8] - bf2f(h1));
        }
      }
    }
    {
      const unsigned short* bp = Bhig + (size_t)(n0 + sr) * K + k0 + kh;
      bh0 = *(const s16x8*)bp; bh1 = *(const s16x8*)(bp + 8);
      if constexpr (SPLIT) {
        const unsigned short* bq = Blog + (size_t)(n0 + sr) * K + k0 + kh;
        bl0 = *(const s16x8*)bq; bl1 = *(const s16x8*)(bq + 8);
      }
    }
    __syncthreads();
    *(s16x8*)(sAhi + db0) = ah0; *(s16x8*)(sAhi + db1) = ah1;
    *(s16x8*)(sBhi + db0) = bh0; *(s16x8*)(sBhi + db1) = bh1;
    if constexpr (SPLIT) {
      *(s16x8*)(sAlo + db0) = al0; *(s16x8*)(sAlo + db1) = al1;
      *(s16x8*)(sBlo + db0) = bl0; *(s16x8*)(sBlo + db1) = bl1;
    }
    __syncthreads();

    s16x8 Af[4], Al[4], Bf[4], Bl[4];
    #pragma unroll
    for (int i = 0; i < 4; ++i) {
      const int off = (wr * 64 + i * 16 + fr) * 64 + ((kc * 16) ^ fsw);
      Af[i] = *(const s16x8*)(sAhi + off);
      if constexpr (SPLIT) Al[i] = *(const s16x8*)(sAlo + off);
    }
    #pragma unroll
    for (int j = 0; j < 4; ++j) {
      const int off = (wc * 64 + j * 16 + fr) * 64 + ((kc * 16) ^ fsw);
      Bf[j] = *(const s16x8*)(sBhi + off);
      if constexpr (SPLIT) Bl[j] = *(const s16x8*)(sBlo + off);
    }
    #pragma unroll
    for (int i = 0; i < 4; ++i)
      #pragma unroll
      for (int j = 0; j < 4; ++j) {
        acc[i][j] = __builtin_amdgcn_mfma_f32_16x16x32_bf16(Af[i], Bf[j], acc[i][j], 0, 0, 0);
        if constexpr (SPLIT) {
          acc[i][j] = __builtin_amdgcn_mfma_f32_16x16x32_bf16(Af[i], Bl[j], acc[i][j], 0, 0, 0);
          acc[i][j] = __builtin_amdgcn_mfma_f32_16x16x32_bf16(Al[i], Bf[j], acc[i][j], 0, 0, 0);
        }
      }
  }

  #pragma unroll
  for (int i = 0; i < 4; ++i)
    #pragma unroll
    for (int j = 0; j < 4; ++j) {
      const int col = n0 + wc * 64 + j * 16 + fr;
      #pragma unroll
      for (int rr = 0; rr < 4; ++rr) {
        const int row = m0 + wr * 64 + i * 16 + kc * 4 + rr;
        const float v = acc[i][j][rr];
        if constexpr (MODE == 1) {
          const int g = col >> 8;
          const float sg = (g == 0) ? 1.0f : ((g == 1) ? 1.41421356237309515f : 2.0f);
          const float z = cosf(v * sg + bias[col]) * 0.08838834764831845f;
          Cb[(size_t)row * N + col] = f2bf(z);
        } else {
          Cf[(size_t)row * N + col] = v + bias[col];
        }
      }
    }
}

// ======================== RoPE table + apply ================================
__global__ __launch_bounds__(256) void rope_table_kernel(float2* __restrict__ tab)
{
  const int idx = blockIdx.x * 256 + threadIdx.x;
  const int j = idx & 31, s = idx >> 5;
  const double inv = pow(10000.0, -(double)j * (1.0 / 32.0));
  double sd, cd;
  sincos((double)s * inv, &sd, &cd);
  tab[idx] = make_float2((float)cd, (float)sd);
}

__global__ __launch_bounds__(256) void rope_apply_kernel(
    const float2* __restrict__ tab, float* __restrict__ Q, float* __restrict__ Kb)
{
  const int idx = blockIdx.x * 256 + threadIdx.x;
  const int j = idx & 31;
  const int h = (idx >> 5) & 15;
  const int s = (idx >> 9) & 4095;
  const int b = idx >> 21;
  const float2 cs = tab[(s << 5) | j];
  const float snv = cs.y, csv = cs.x;
  const size_t base = ((size_t)(b * 4096 + s)) * 1024 + h * 64 + j;
  const float q0 = Q[base], q1 = Q[base + 32];
  Q[base]      = q0 * csv - q1 * snv;
  Q[base + 32] = q1 * csv + q0 * snv;
  const float k0 = Kb[base], k1 = Kb[base + 32];
  Kb[base]      = k0 * csv - k1 * snv;
  Kb[base + 32] = k1 * csv + k0 * snv;
}

// ======================== Nystrom RBF features ==============================
__global__ __launch_bounds__(256) void nystrom_kernel(
    const float* __restrict__ Kb, const float* __restrict__ lm,
    float* __restrict__ kny)
{
  __shared__ float lmT[64][65];
  __shared__ float lnorm[64];
  const int tid = threadIdx.x;
  for (int idx = tid; idx < 4096; idx += 256)
    lmT[idx & 63][idx >> 6] = lm[idx];
  if (tid < 64) {
    float s = 0.f;
    #pragma unroll
    for (int d = 0; d < 64; ++d) { const float v = lm[tid * 64 + d]; s = fmaf(v, v, s); }
    lnorm[tid] = s;
  }
  __syncthreads();
  const int lane = tid & 63;
  const int nw = gridDim.x * 4;
  for (int row = blockIdx.x * 4 + (tid >> 6); row < 131072; row += nw) {
    const float kd = Kb[(size_t)row * 64 + lane];
    float nk = kd * kd;
    #pragma unroll
    for (int o = 32; o > 0; o >>= 1) nk += __shfl_xor(nk, o, 64);
    float dot = 0.f;
    #pragma unroll
    for (int d = 0; d < 64; ++d) dot = fmaf(__shfl(kd, d, 64), lmT[d][lane], dot);
    kny[(size_t)row * 64 + lane] = __expf((2.f * dot - nk - lnorm[lane]) * 0.015625f);
  }
}

// ======================== FAVOR-K (MFMA) ====================================
// grid 256 = 32 bh * 8 chunks(512 s); 512 thr, 8 waves, wave owns 32 m.
// MFMA1: S[s][m] = kny . omega  (3-way split). P=exp(S-norm-ln16) -> LDS [m][s].
// MFMA2: KVp[m][n] += P^T x VT  (n: 64 d + ksum(ones) + 15 pad).
__global__ __launch_bounds__(512) void favor_k_mfma(
    const float* __restrict__ kny,
    const unsigned short* __restrict__ oThi, const unsigned short* __restrict__ oTlo,
    const unsigned short* __restrict__ VT, float* __restrict__ KVp)
{
  const int bid = blockIdx.x;
  const int bh = bid >> 3, chunk = bid & 7;
  const int b = bh >> 4, h = bh & 15;
  const int s0 = chunk * 512;
  const int tid = threadIdx.x, lane = tid & 63, wid = tid >> 6;
  const int fr = lane & 15, kc = lane >> 4;
  const int m0w = wid * 32;

  __shared__ unsigned short P[256][40];
  __shared__ float T[8][32][84];

  // resident omega^T frags for this wave's 2 m-colfrags
  s16x8 whi[2][2], wlo[2][2];
  #pragma unroll
  for (int c = 0; c < 2; ++c)
    #pragma unroll
    for (int ks = 0; ks < 2; ++ks) {
      const size_t off = (size_t)(m0w + c * 16 + fr) * 64 + ks * 32 + kc * 8;
      whi[c][ks] = *(const s16x8*)(oThi + off);
      wlo[c][ks] = *(const s16x8*)(oTlo + off);
    }

  f32x4 acc2[2][5];
  #pragma unroll
  for (int i = 0; i < 2; ++i)
    #pragma unroll
    for (int j = 0; j < 5; ++j) acc2[i][j] = f32x4{0.f, 0.f, 0.f, 0.f};

  for (int st = 0; st < 512; st += 32) {
    // A loads (kny rows) + norms
    s16x8 ahi[2][2], alo[2][2];
    float nrm[2];
    #pragma unroll
    for (int r = 0; r < 2; ++r) {
      float part = 0.f;
      #pragma unroll
      for (int ks = 0; ks < 2; ++ks) {
        const float* ap = kny +
            ((size_t)((b * 4096 + s0 + st + r * 16 + fr) * 16 + h)) * 64 + ks * 32 + kc * 8;
        const float4 f0 = ((const float4*)ap)[0];
        const float4 f1 = ((const float4*)ap)[1];
        float v[8] = {f0.x, f0.y, f0.z, f0.w, f1.x, f1.y, f1.z, f1.w};
        #pragma unroll
        for (int u = 0; u < 8; ++u) {
          part = fmaf(v[u], v[u], part);
          const unsigned short hh = f2bf(v[u]);
          ahi[r][ks][u] = (short)hh;
          alo[r][ks][u] = (short)f2bf(v[u] - bf2f(hh));
        }
      }
      part += __shfl_xor(part, 16);
      part += __shfl_xor(part, 32);
      nrm[r] = 0.5f * part;
    }
    __syncthreads();   // protect prior iteration's P reads (WAR)
    // MFMA1 + exp -> P [m][s]
    #pragma unroll
    for (int r = 0; r < 2; ++r)
      #pragma unroll
      for (int c = 0; c < 2; ++c) {
        f32x4 s1 = f32x4{0.f, 0.f, 0.f, 0.f};
        #pragma unroll
        for (int ks = 0; ks < 2; ++ks) {
          s1 = __builtin_amdgcn_mfma_f32_16x16x32_bf16(alo[r][ks], whi[c][ks], s1, 0, 0, 0);
          s1 = __builtin_amdgcn_mfma_f32_16x16x32_bf16(ahi[r][ks], wlo[c][ks], s1, 0, 0, 0);
          s1 = __builtin_amdgcn_mfma_f32_16x16x32_bf16(ahi[r][ks], whi[c][ks], s1, 0, 0, 0);
        }
        #pragma unroll
        for (int reg = 0; reg < 4; ++reg) {
          const int sl = kc * 4 + reg;
          const float nn = __shfl(nrm[r], sl);
          const float p = __expf(s1[reg] - nn - 2.772588722239781f);
          P[m0w + c * 16 + fr][r * 16 + sl] = f2bf(p);
        }
      }
    __syncthreads();   // P visible (cross-lane within wave)
    // MFMA2: contract over the 32 s of this tile
    s16x8 b2[5];
    #pragma unroll
    for (int nf = 0; nf < 5; ++nf)
      b2[nf] = *(const s16x8*)(VT + ((size_t)bh * 80 + nf * 16 + fr) * 4096 +
                               s0 + st + kc * 8);
    #pragma unroll
    for (int mf = 0; mf < 2; ++mf) {
      const s16x8 a2 = *(const s16x8*)&P[m0w + mf * 16 + fr][kc * 8];
      #pragma unroll
      for (int nf = 0; nf < 5; ++nf)
        acc2[mf][nf] = __builtin_amdgcn_mfma_f32_16x16x32_bf16(a2, b2[nf], acc2[mf][nf], 0, 0, 0);
    }
  }
  // epilogue: LDS transpose -> KVp[bid][n][m] coalesced
  #pragma unroll
  for (int mf = 0; mf < 2; ++mf)
    #pragma unroll
    for (int nf = 0; nf < 5; ++nf)
      #pragma unroll
      for (int reg = 0; reg < 4; ++reg)
        T[wid][mf * 16 + kc * 4 + reg][nf * 16 + fr] = acc2[mf][nf][reg];
  __syncthreads();
  #pragma unroll
  for (int i = 0; i < 40; ++i) {
    const int flat = i * 64 + lane;
    const int n = flat >> 5, ml = flat & 31;
    KVp[((size_t)bid * 80 + n) * 256 + m0w + ml] = T[wid][ml][n];
  }
}

// ======================== reduce KVp -> KVXT bf16 ===========================
// KVXT[bh][n][m] = bf16( sum_c KVp[bh*8+c][n][m] )
__global__ __launch_bounds__(256) void reduce_kvxt_kernel(
    const float* __restrict__ KVp, unsigned short* __restrict__ KVXT)
{
  const int bh = blockIdx.x;
  const int m = threadIdx.x;
  for (int n = 0; n < 80; ++n) {
    float s = 0.f;
    #pragma unroll
    for (int c = 0; c < 8; ++c)
      s += KVp[((size_t)(bh * 8 + c) * 80 + n) * 256 + m];
    KVXT[((size_t)bh * 80 + n) * 256 + m] = f2bf(s);
  }
}

// ======================== FAVOR-Q (MFMA) ====================================
// grid 512 = 32 bh * 16 chunks(256 s); 512 thr, wave owns 32 s-rows.
// MFMA1: S[s][m]=Q.omega (split). P=exp(S-norm-ln16) -> per-wave LDS [s][m64].
// MFMA2: OUT[s][n] += P x KVXT (n: 64 d + denom col). O bf16.
__global__ __launch_bounds__(512) void favor_q_mfma(
    const float* __restrict__ Q,
    const unsigned short* __restrict__ oThi, const unsigned short* __restrict__ oTlo,
    const unsigned short* __restrict__ KVXT, unsigned short* __restrict__ O)
{
  const int bid = blockIdx.x;
  const int bh = bid >> 4, chunk = bid & 15;
  const int b = bh >> 4, h = bh & 15;
  const int s0 = chunk * 256;
  const int tid = threadIdx.x, lane = tid & 63, wid = tid >> 6;
  const int fr = lane & 15, kc = lane >> 4;
  const int ws0 = s0 + wid * 32;

  __shared__ unsigned short KX[80][264];
  __shared__ unsigned short P[8][32][66];

  for (int i = tid; i < 80 * 256; i += 512)
    KX[i >> 8][i & 255] = KVXT[(size_t)bh * 80 * 256 + i];
  __syncthreads();

  // resident A (Q rows) hi/lo + norms
  s16x8 ahi[2][2], alo[2][2];
  float nrm[2];
  #pragma unroll
  for (int r = 0; r < 2; ++r) {
    float part = 0.f;
    #pragma unroll
    for (int ks = 0; ks < 2; ++ks) {
      const float* ap = Q + ((size_t)(b * 4096 + ws0 + r * 16 + fr)) * 1024 +
                        h * 64 + ks * 32 + kc * 8;
      const float4 f0 = ((const float4*)ap)[0];
      const float4 f1 = ((const float4*)ap)[1];
      float v[8] = {f0.x, f0.y, f0.z, f0.w, f1.x, f1.y, f1.z, f1.w};
      #pragma unroll
      for (int u = 0; u < 8; ++u) {
        part = fmaf(v[u], v[u], part);
        const unsigned short hh = f2bf(v[u]);
        ahi[r][ks][u] = (short)hh;
        alo[r][ks][u] = (short)f2bf(v[u] - bf2f(hh));
      }
    }
    part += __shfl_xor(part, 16);
    part += __shfl_xor(part, 32);
    nrm[r] = 0.5f * part;
  }

  f32x4 acc2[2][5];
  #pragma unroll
  for (int i = 0; i < 2; ++i)
    #pragma unroll
    for (int j = 0; j < 5; ++j) acc2[i][j] = f32x4{0.f, 0.f, 0.f, 0.f};

  for (int mc = 0; mc < 4; ++mc) {
    __syncthreads();   // protect prior chunk's P reads (WAR)
    #pragma unroll
    for (int r = 0; r < 2; ++r)
      #pragma unroll
      for (int c = 0; c < 4; ++c) {
        f32x4 s1 = f32x4{0.f, 0.f, 0.f, 0.f};
        #pragma unroll
        for (int ks = 0; ks < 2; ++ks) {
          const size_t off = (size_t)(mc * 64 + c * 16 + fr) * 64 + ks * 32 + kc * 8;
          const s16x8 bh1 = *(const s16x8*)(oThi + off);
          const s16x8 bl1 = *(const s16x8*)(oTlo + off);
          s1 = __builtin_amdgcn_mfma_f32_16x16x32_bf16(alo[r][ks], bh1, s1, 0, 0, 0);
          s1 = __builtin_amdgcn_mfma_f32_16x16x32_bf16(ahi[r][ks], bl1, s1, 0, 0, 0);
          s1 = __builtin_amdgcn_mfma_f32_16x16x32_bf16(ahi[r][ks], bh1, s1, 0, 0, 0);
        }
        #pragma unroll
        for (int reg = 0; reg < 4; ++reg) {
          const int sl = kc * 4 + reg;
          const float nn = __shfl(nrm[r], sl);
          const float p = __expf(s1[reg] - nn - 2.772588722239781f);
          P[wid][r * 16 + sl][c * 16 + fr] = f2bf(p);
        }
      }
    __syncthreads();   // P visible
    #pragma unroll
    for (int ks2 = 0; ks2 < 2; ++ks2) {
      s16x8 b2[5];
      #pragma unroll
      for (int nf = 0; nf < 5; ++nf)
        b2[nf] = *(const s16x8*)&KX[nf * 16 + fr][mc * 64 + ks2 * 32 + kc * 8];
      #pragma unroll
      for (int r = 0; r < 2; ++r) {
        const s16x8 a2 = *(const s16x8*)&P[wid][r * 16 + fr][ks2 * 32 + kc * 8];
        #pragma unroll
        for (int nf = 0; nf < 5; ++nf)
          acc2[r][nf] = __builtin_amdgcn_mfma_f32_16x16x32_bf16(a2, b2[nf], acc2[r][nf], 0, 0, 0);
      }
    }
  }
  // epilogue: out = num/(denom+eps), write bf16
  #pragma unroll
  for (int r = 0; r < 2; ++r)
    #pragma unroll
    for (int reg = 0; reg < 4; ++reg) {
      const int s = ws0 + r * 16 + kc * 4 + reg;
      const float dv = __shfl(acc2[r][4][reg], lane & 48) + 1e-6f;
      #pragma unroll
      for (int nf = 0; nf < 4; ++nf)
        O[(size_t)(b * 4096 + s) * 1024 + h * 64 + nf * 16 + fr] =
            f2bf(acc2[r][nf][reg] / dv);
    }
}

// ======================== launcher ==========================================
extern "C" void kernel_launch(void* const* d_in, const int* in_sizes, int n_in,
                              void* d_out, int out_size, void* d_ws, size_t ws_size,
                              hipStream_t stream)
{
  const float* x      = (const float*)d_in[0];
  const float* conv_k = (const float*)d_in[1];
  const float* conv_b = (const float*)d_in[2];
  const float* rff_w  = (const float*)d_in[3];
  const float* rff_b  = (const float*)d_in[4];
  const float* proj_w = (const float*)d_in[5];
  const float* proj_b = (const float*)d_in[6];
  const float* omega  = (const float*)d_in[7];
  const float* lm     = (const float*)d_in[8];
  const float* out_w  = (const float*)d_in[9];
  const float* out_b  = (const float*)d_in[10];

  char* wsb = (char*)d_ws;
  size_t o = 0;
  auto alloc = [&](size_t bytes) {
    char* p = wsb + o;
    o = (o + bytes + 255) & ~(size_t)255;
    return p;
  };
  unsigned short* Wc_hi = (unsigned short*)alloc(4718592);
  unsigned short* Wc_lo = (unsigned short*)alloc(4718592);
  unsigned short* Wr_hi = (unsigned short*)alloc(4718592);
  unsigned short* Wr_lo = (unsigned short*)alloc(4718592);
  unsigned short* Wp    = (unsigned short*)alloc(4718592);
  unsigned short* Wo    = (unsigned short*)alloc(2097152);
  float* hbuf  = (float*)alloc(33554432);          // h f32; later kny
  unsigned short* feats = (unsigned short*)alloc(12582912);
  float* Qb = (float*)alloc(33554432);
  float* Kb = (float*)alloc(33554432);
  float* Vb = (float*)alloc(33554432);
  float2* tab = (float2*)alloc(1048576);
  unsigned short* oThi = (unsigned short*)alloc(32768);
  unsigned short* oTlo = (unsigned short*)alloc(32768);
  unsigned short* VT   = (unsigned short*)alloc(20971520);   // 32*80*4096*2
  float* KVp = (float*)alloc(20971520);                      // 256*80*256*4
  unsigned short* KVXT = (unsigned short*)alloc(1310720);    // 32*80*256*2
  unsigned short* Obf  = (unsigned short*)alloc(16777216);

  dim3 blk(256);
  wconv_kernel<0><<<dim3(12, 16, 3), blk, 0, stream>>>(conv_k, Wc_hi, Wc_lo);
  wconv_kernel<1><<<dim3(16, 4, 9),  blk, 0, stream>>>(rff_w, Wr_hi, Wr_lo);
  wconv_kernel<2><<<dim3(12, 16, 3), blk, 0, stream>>>(proj_w, Wp, nullptr);
  wconv_kernel<3><<<dim3(16, 16, 1), blk, 0, stream>>>(out_w, Wo, nullptr);
  omega_prep_kernel<<<64, blk, 0, stream>>>(omega, oThi, oTlo);
  rope_table_kernel<<<512, blk, 0, stream>>>(tab);

  float* qkv[3] = {Qb, Kb, Vb};
  for (int i = 0; i < 3; ++i) {
    gemm_mfma<0><<<dim3(8, 64), blk, 0, stream>>>(
        x, Wc_hi + (size_t)i * 786432, Wc_lo + (size_t)i * 786432,
        conv_b + i * 1024, hbuf, nullptr, 8192, 1024, 768);
    gemm_mfma<1><<<dim3(6, 64), blk, 0, stream>>>(
        hbuf, Wr_hi + (size_t)i * 786432, Wr_lo + (size_t)i * 786432,
        rff_b + i * 768, nullptr, feats, 8192, 768, 1024);
    gemm_mfma<2><<<dim3(8, 64), blk, 0, stream>>>(
        feats, Wp + (size_t)i * 786432, nullptr,
        proj_b + i * 1024, qkv[i], nullptr, 8192, 1024, 768);
  }
  rope_apply_kernel<<<16384, blk, 0, stream>>>(tab, Qb, Kb);
  vt_kernel<<<dim3(32, 64), blk, 0, stream>>>(Vb, VT);
  vt_fill_kernel<<<8192, blk, 0, stream>>>(VT);
  nystrom_kernel<<<512, blk, 0, stream>>>(Kb, lm, hbuf);
  favor_k_mfma<<<256, dim3(512), 0, stream>>>(hbuf, oThi, oTlo, VT, KVp);
  reduce_kvxt_kernel<<<32, blk, 0, stream>>>(KVp, KVXT);
  favor_q_mfma<<<512, dim3(512), 0, stream>>>(Qb, oThi, oTlo, KVXT, Obf);
  gemm_mfma<2><<<dim3(8, 64), blk, 0, stream>>>(
      Obf, Wo, nullptr, out_b, (float*)d_out, nullptr, 8192, 1024, 1024);
}

// Round 5
// 1198.031 us; speedup vs baseline: 2.2627x; 1.0045x over previous
//
#include <hip/hip_runtime.h>
#include <math.h>

// ---------------------------------------------------------------------------
// B=2, S=4096, C=1024, H=16, Dh=64, G=3, Ms=256, NRF=256, L=64
// Round 5: round-4 design (pre-converted bf16 hi/lo GEMM operands) with the
// LDS byte-addressing fix (offsets were already in bytes; the *2 clobbered
// adjacent LDS regions).
// ---------------------------------------------------------------------------

using f32x4 = __attribute__((ext_vector_type(4))) float;
using s16x8 = __attribute__((ext_vector_type(8))) short;

__device__ __forceinline__ unsigned short f2bf(float x) {
  unsigned u = __float_as_uint(x);
  unsigned r = u + 0x7fffu + ((u >> 16) & 1u);
  return (unsigned short)(r >> 16);
}
__device__ __forceinline__ float bf2f(unsigned short h) {
  return __uint_as_float(((unsigned)h) << 16);
}

// ======================== f32 -> bf16 hi/lo splitter ========================
__global__ __launch_bounds__(256) void split_prep_kernel(
    const float* __restrict__ in, unsigned short* __restrict__ ohi,
    unsigned short* __restrict__ olo, int n8)
{
  const int i = blockIdx.x * 256 + threadIdx.x;
  if (i >= n8) return;
  const float4 f0 = ((const float4*)in)[i * 2];
  const float4 f1 = ((const float4*)in)[i * 2 + 1];
  const float v[8] = {f0.x, f0.y, f0.z, f0.w, f1.x, f1.y, f1.z, f1.w};
  s16x8 hi, lo;
  #pragma unroll
  for (int u = 0; u < 8; ++u) {
    const unsigned short hh = f2bf(v[u]);
    hi[u] = (short)hh;
    lo[u] = (short)f2bf(v[u] - bf2f(hh));
  }
  ((s16x8*)ohi)[i] = hi;
  ((s16x8*)olo)[i] = lo;
}

// ======================== weight transpose + convert ========================
template<int WM>  // 0 conv(3i, split) 1 rff(9 z=i*3+g, split) 2 proj(3i) 3 out_w
__global__ __launch_bounds__(256) void wconv_kernel(
    const float* __restrict__ in0, unsigned short* __restrict__ ohi,
    unsigned short* __restrict__ olo)
{
  int K, N;
  const float* in;
  unsigned short *oh, *ol = nullptr;
  const int z = blockIdx.z;
  if constexpr (WM == 0) {
    K = 768; N = 1024;
    in = in0 + (size_t)z * 786432;
    oh = ohi + (size_t)z * 786432; ol = olo + (size_t)z * 786432;
  } else if constexpr (WM == 1) {
    K = 1024; N = 256;
    const int i = z / 3, g = z % 3;
    in = in0 + (size_t)i * 786432 + (size_t)g * 262144;
    oh = ohi + (size_t)i * 786432 + (size_t)g * 262144;
    ol = olo + (size_t)i * 786432 + (size_t)g * 262144;
  } else if constexpr (WM == 2) {
    K = 768; N = 1024;
    in = in0 + (size_t)z * 786432; oh = ohi + (size_t)z * 786432;
  } else {
    K = 1024; N = 1024; in = in0; oh = ohi;
  }
  const int k0 = blockIdx.x * 64, n0 = blockIdx.y * 64;
  __shared__ float t[64][65];
  const int tid = threadIdx.x, tn = tid & 63, tr = tid >> 6;
  #pragma unroll 4
  for (int p = 0; p < 16; ++p) {
    const int kk = p * 4 + tr;
    t[kk][tn] = in[(size_t)(k0 + kk) * N + n0 + tn];
  }
  __syncthreads();
  #pragma unroll 4
  for (int p = 0; p < 16; ++p) {
    const int nn = p * 4 + tr;
    const float v = t[tn][nn];
    const unsigned short hi = f2bf(v);
    oh[(size_t)(n0 + nn) * K + k0 + tn] = hi;
    if constexpr (WM <= 1)
      ol[(size_t)(n0 + nn) * K + k0 + tn] = f2bf(v - bf2f(hi));
  }
}

// omega [64][256] f32 -> omegaT [256][64] bf16 hi/lo
__global__ __launch_bounds__(256) void omega_prep_kernel(
    const float* __restrict__ omega, unsigned short* __restrict__ oThi,
    unsigned short* __restrict__ oTlo)
{
  const int idx = blockIdx.x * 256 + threadIdx.x;  // 16384
  const int m = idx >> 6, d = idx & 63;
  const float v = omega[d * 256 + m];
  const unsigned short hi = f2bf(v);
  oThi[idx] = hi;
  oTlo[idx] = f2bf(v - bf2f(hi));
}

// V [8192][1024] f32 -> VT[bh][80][4096] bf16 (rows 0..63 = V^T per head)
__global__ __launch_bounds__(256) void vt_kernel(
    const float* __restrict__ V, unsigned short* __restrict__ VT)
{
  const int bh = blockIdx.x, sb = blockIdx.y;
  const int b = bh >> 4, h = bh & 15;
  __shared__ float t[64][65];
  const int tid = threadIdx.x, tn = tid & 63, tr = tid >> 6;
  #pragma unroll 4
  for (int p = 0; p < 16; ++p)
    t[p * 4 + tr][tn] =
        V[(size_t)(b * 4096 + sb * 64 + p * 4 + tr) * 1024 + h * 64 + tn];
  __syncthreads();
  #pragma unroll 4
  for (int p = 0; p < 16; ++p)
    VT[((size_t)bh * 80 + p * 4 + tr) * 4096 + sb * 64 + tn] =
        f2bf(t[tn][p * 4 + tr]);
}

// VT rows 64..79: row 64 = 1.0 (ksum column), rows 65..79 = 0
__global__ __launch_bounds__(256) void vt_fill_kernel(unsigned short* __restrict__ VT)
{
  const int idx = blockIdx.x * 256 + threadIdx.x;  // 32*16*4096
  const int s = idx & 4095, rr = (idx >> 12) & 15, bh = idx >> 16;
  VT[((size_t)bh * 80 + 64 + rr) * 4096 + s] = (rr == 0) ? 0x3F80 : 0;
}

// ======================== MFMA GEMM (all-bf16 operands) =====================
// 128x128 tile, BK=32, 256 threads (2x2 waves), 16x16x32 bf16 MFMA.
// LDS offsets are BYTE offsets (row stride 64 B = 32 bf16).
template<int MODE>
__global__ __launch_bounds__(256, MODE == 2 ? 4 : 3) void gemm_mfma(
    const unsigned short* __restrict__ Ahi, const unsigned short* __restrict__ Alo,
    const unsigned short* __restrict__ Bhig, const unsigned short* __restrict__ Blog,
    const float* __restrict__ bias,
    float* __restrict__ Cf, unsigned short* __restrict__ C1,
    unsigned short* __restrict__ C2,
    int M, int N, int K)
{
  constexpr bool SPLIT = (MODE <= 1);
  __shared__ alignas(16) char smem[SPLIT ? 32768 : 16384];
  char* const sAhi = smem;
  char* const sBhi = smem + (SPLIT ? 16384 : 8192);
  char* const sAlo = smem + 8192;
  char* const sBlo = smem + 24576;

  const int tid = threadIdx.x;
  const int n0 = blockIdx.x * 128;
  const int m0 = blockIdx.y * 128;

  const int sr = tid >> 1;          // staged row 0..127
  const int kh = (tid & 1) * 16;    // k offset 0/16 (elements)
  const int sw = ((sr >> 1) & 3) << 4;          // byte swizzle
  const int c0 = kh >> 3;                       // 16B chunk index 0 or 2
  const int db0 = sr * 64 + ((c0 * 16) ^ sw);   // BYTE offset
  const int db1 = sr * 64 + (((c0 + 1) * 16) ^ sw);

  const int lane = tid & 63, wid = tid >> 6;
  const int wr = wid >> 1, wc = wid & 1;
  const int fr = lane & 15, kc = lane >> 4;
  const int fsw = ((fr >> 1) & 3) << 4;

  f32x4 acc[4][4];
  #pragma unroll
  for (int i = 0; i < 4; ++i)
    #pragma unroll
    for (int j = 0; j < 4; ++j) acc[i][j] = f32x4{0.f, 0.f, 0.f, 0.f};

  for (int k0 = 0; k0 < K; k0 += 32) {
    s16x8 ah0, ah1, al0, al1, bh0, bh1, bl0, bl1;
    // ---- A global -> regs (bf16 direct) ----
    if constexpr (MODE == 0) {
      const int grow = m0 + sr;
      const int bb = grow >> 12, s = grow & 4095;
      const int t = k0 >> 8;
      const int ss = s + t - 1;
      const bool valid = ((unsigned)ss < 4096u);
      const int ci = (k0 & 255) + kh;
      const size_t off =
          ((size_t)(bb * 4096 + (valid ? ss : 0))) * 1024 + (n0 >> 8) * 256 + ci;
      if (valid) {
        ah0 = *(const s16x8*)(Ahi + off); ah1 = *(const s16x8*)(Ahi + off + 8);
        al0 = *(const s16x8*)(Alo + off); al1 = *(const s16x8*)(Alo + off + 8);
      } else {
        #pragma unroll
        for (int u = 0; u < 8; ++u) { ah0[u] = 0; ah1[u] = 0; al0[u] = 0; al1[u] = 0; }
      }
    } else {
      const size_t off = (size_t)(m0 + sr) * K + k0 + kh;
      ah0 = *(const s16x8*)(Ahi + off); ah1 = *(const s16x8*)(Ahi + off + 8);
      if constexpr (SPLIT) {
        al0 = *(const s16x8*)(Alo + off); al1 = *(const s16x8*)(Alo + off + 8);
      }
    }
    // ---- B global -> regs ----
    {
      const size_t off = (size_t)(n0 + sr) * K + k0 + kh;
      bh0 = *(const s16x8*)(Bhig + off); bh1 = *(const s16x8*)(Bhig + off + 8);
      if constexpr (SPLIT) {
        bl0 = *(const s16x8*)(Blog + off); bl1 = *(const s16x8*)(Blog + off + 8);
      }
    }
    __syncthreads();
    *(s16x8*)(sAhi + db0) = ah0; *(s16x8*)(sAhi + db1) = ah1;
    *(s16x8*)(sBhi + db0) = bh0; *(s16x8*)(sBhi + db1) = bh1;
    if constexpr (SPLIT) {
      *(s16x8*)(sAlo + db0) = al0; *(s16x8*)(sAlo + db1) = al1;
      *(s16x8*)(sBlo + db0) = bl0; *(s16x8*)(sBlo + db1) = bl1;
    }
    __syncthreads();

    s16x8 Af[4], Al[4], Bf[4], Bl[4];
    #pragma unroll
    for (int i = 0; i < 4; ++i) {
      const int off = (wr * 64 + i * 16 + fr) * 64 + ((kc * 16) ^ fsw);
      Af[i] = *(const s16x8*)(sAhi + off);
      if constexpr (SPLIT) Al[i] = *(const s16x8*)(sAlo + off);
    }
    #pragma unroll
    for (int j = 0; j < 4; ++j) {
      const int off = (wc * 64 + j * 16 + fr) * 64 + ((kc * 16) ^ fsw);
      Bf[j] = *(const s16x8*)(sBhi + off);
      if constexpr (SPLIT) Bl[j] = *(const s16x8*)(sBlo + off);
    }
    #pragma unroll
    for (int i = 0; i < 4; ++i)
      #pragma unroll
      for (int j = 0; j < 4; ++j) {
        acc[i][j] = __builtin_amdgcn_mfma_f32_16x16x32_bf16(Af[i], Bf[j], acc[i][j], 0, 0, 0);
        if constexpr (SPLIT) {
          acc[i][j] = __builtin_amdgcn_mfma_f32_16x16x32_bf16(Af[i], Bl[j], acc[i][j], 0, 0, 0);
          acc[i][j] = __builtin_amdgcn_mfma_f32_16x16x32_bf16(Al[i], Bf[j], acc[i][j], 0, 0, 0);
        }
      }
  }

  // ---- epilogue ----
  #pragma unroll
  for (int i = 0; i < 4; ++i)
    #pragma unroll
    for (int j = 0; j < 4; ++j) {
      const int col = n0 + wc * 64 + j * 16 + fr;
      #pragma unroll
      for (int rr = 0; rr < 4; ++rr) {
        const int row = m0 + wr * 64 + i * 16 + kc * 4 + rr;
        const float v = acc[i][j][rr];
        if constexpr (MODE == 0) {
          const float hv = v + bias[col];
          const unsigned short hh = f2bf(hv);
          C1[(size_t)row * N + col] = hh;
          C2[(size_t)row * N + col] = f2bf(hv - bf2f(hh));
        } else if constexpr (MODE == 1) {
          const int g = col >> 8;
          const float sg = (g == 0) ? 1.0f : ((g == 1) ? 1.41421356237309515f : 2.0f);
          const float z = cosf(v * sg + bias[col]) * 0.08838834764831845f;
          C1[(size_t)row * N + col] = f2bf(z);
        } else {
          Cf[(size_t)row * N + col] = v + bias[col];
        }
      }
    }
}

// ======================== RoPE table + apply ================================
__global__ __launch_bounds__(256) void rope_table_kernel(float2* __restrict__ tab)
{
  const int idx = blockIdx.x * 256 + threadIdx.x;
  const int j = idx & 31, s = idx >> 5;
  const double inv = pow(10000.0, -(double)j * (1.0 / 32.0));
  double sd, cd;
  sincos((double)s * inv, &sd, &cd);
  tab[idx] = make_float2((float)cd, (float)sd);
}

__global__ __launch_bounds__(256) void rope_apply_kernel(
    const float2* __restrict__ tab, float* __restrict__ Q, float* __restrict__ Kb)
{
  const int idx = blockIdx.x * 256 + threadIdx.x;
  const int j = idx & 31;
  const int h = (idx >> 5) & 15;
  const int s = (idx >> 9) & 4095;
  const int b = idx >> 21;
  const float2 cs = tab[(s << 5) | j];
  const float snv = cs.y, csv = cs.x;
  const size_t base = ((size_t)(b * 4096 + s)) * 1024 + h * 64 + j;
  const float q0 = Q[base], q1 = Q[base + 32];
  Q[base]      = q0 * csv - q1 * snv;
  Q[base + 32] = q1 * csv + q0 * snv;
  const float k0 = Kb[base], k1 = Kb[base + 32];
  Kb[base]      = k0 * csv - k1 * snv;
  Kb[base + 32] = k1 * csv + k0 * snv;
}

// ======================== Nystrom RBF features ==============================
__global__ __launch_bounds__(256) void nystrom_kernel(
    const float* __restrict__ Kb, const float* __restrict__ lm,
    float* __restrict__ kny)
{
  __shared__ float lmT[64][65];
  __shared__ float lnorm[64];
  const int tid = threadIdx.x;
  for (int idx = tid; idx < 4096; idx += 256)
    lmT[idx & 63][idx >> 6] = lm[idx];
  if (tid < 64) {
    float s = 0.f;
    #pragma unroll
    for (int d = 0; d < 64; ++d) { const float v = lm[tid * 64 + d]; s = fmaf(v, v, s); }
    lnorm[tid] = s;
  }
  __syncthreads();
  const int lane = tid & 63;
  const int nw = gridDim.x * 4;
  for (int row = blockIdx.x * 4 + (tid >> 6); row < 131072; row += nw) {
    const float kd = Kb[(size_t)row * 64 + lane];
    float nk = kd * kd;
    #pragma unroll
    for (int o = 32; o > 0; o >>= 1) nk += __shfl_xor(nk, o, 64);
    float dot = 0.f;
    #pragma unroll
    for (int d = 0; d < 64; ++d) dot = fmaf(__shfl(kd, d, 64), lmT[d][lane], dot);
    kny[(size_t)row * 64 + lane] = __expf((2.f * dot - nk - lnorm[lane]) * 0.015625f);
  }
}

// ======================== FAVOR-K (MFMA) ====================================
__global__ __launch_bounds__(512) void favor_k_mfma(
    const float* __restrict__ kny,
    const unsigned short* __restrict__ oThi, const unsigned short* __restrict__ oTlo,
    const unsigned short* __restrict__ VT, float* __restrict__ KVp)
{
  const int bid = blockIdx.x;
  const int bh = bid >> 3, chunk = bid & 7;
  const int b = bh >> 4, h = bh & 15;
  const int s0 = chunk * 512;
  const int tid = threadIdx.x, lane = tid & 63, wid = tid >> 6;
  const int fr = lane & 15, kc = lane >> 4;
  const int m0w = wid * 32;

  __shared__ unsigned short P[256][40];
  __shared__ float T[8][32][84];

  s16x8 whi[2][2], wlo[2][2];
  #pragma unroll
  for (int c = 0; c < 2; ++c)
    #pragma unroll
    for (int ks = 0; ks < 2; ++ks) {
      const size_t off = (size_t)(m0w + c * 16 + fr) * 64 + ks * 32 + kc * 8;
      whi[c][ks] = *(const s16x8*)(oThi + off);
      wlo[c][ks] = *(const s16x8*)(oTlo + off);
    }

  f32x4 acc2[2][5];
  #pragma unroll
  for (int i = 0; i < 2; ++i)
    #pragma unroll
    for (int j = 0; j < 5; ++j) acc2[i][j] = f32x4{0.f, 0.f, 0.f, 0.f};

  for (int st = 0; st < 512; st += 32) {
    s16x8 ahi[2][2], alo[2][2];
    float nrm[2];
    #pragma unroll
    for (int r = 0; r < 2; ++r) {
      float part = 0.f;
      #pragma unroll
      for (int ks = 0; ks < 2; ++ks) {
        const float* ap = kny +
            ((size_t)((b * 4096 + s0 + st + r * 16 + fr) * 16 + h)) * 64 + ks * 32 + kc * 8;
        const float4 f0 = ((const float4*)ap)[0];
        const float4 f1 = ((const float4*)ap)[1];
        float v[8] = {f0.x, f0.y, f0.z, f0.w, f1.x, f1.y, f1.z, f1.w};
        #pragma unroll
        for (int u = 0; u < 8; ++u) {
          part = fmaf(v[u], v[u], part);
          const unsigned short hh = f2bf(v[u]);
          ahi[r][ks][u] = (short)hh;
          alo[r][ks][u] = (short)f2bf(v[u] - bf2f(hh));
        }
      }
      part += __shfl_xor(part, 16);
      part += __shfl_xor(part, 32);
      nrm[r] = 0.5f * part;
    }
    __syncthreads();
    #pragma unroll
    for (int r = 0; r < 2; ++r)
      #pragma unroll
      for (int c = 0; c < 2; ++c) {
        f32x4 s1 = f32x4{0.f, 0.f, 0.f, 0.f};
        #pragma unroll
        for (int ks = 0; ks < 2; ++ks) {
          s1 = __builtin_amdgcn_mfma_f32_16x16x32_bf16(alo[r][ks], whi[c][ks], s1, 0, 0, 0);
          s1 = __builtin_amdgcn_mfma_f32_16x16x32_bf16(ahi[r][ks], wlo[c][ks], s1, 0, 0, 0);
          s1 = __builtin_amdgcn_mfma_f32_16x16x32_bf16(ahi[r][ks], whi[c][ks], s1, 0, 0, 0);
        }
        #pragma unroll
        for (int reg = 0; reg < 4; ++reg) {
          const int sl = kc * 4 + reg;
          const float nn = __shfl(nrm[r], sl);
          const float p = __expf(s1[reg] - nn - 2.772588722239781f);
          P[m0w + c * 16 + fr][r * 16 + sl] = f2bf(p);
        }
      }
    __syncthreads();
    s16x8 b2[5];
    #pragma unroll
    for (int nf = 0; nf < 5; ++nf)
      b2[nf] = *(const s16x8*)(VT + ((size_t)bh * 80 + nf * 16 + fr) * 4096 +
                               s0 + st + kc * 8);
    #pragma unroll
    for (int mf = 0; mf < 2; ++mf) {
      const s16x8 a2 = *(const s16x8*)&P[m0w + mf * 16 + fr][kc * 8];
      #pragma unroll
      for (int nf = 0; nf < 5; ++nf)
        acc2[mf][nf] = __builtin_amdgcn_mfma_f32_16x16x32_bf16(a2, b2[nf], acc2[mf][nf], 0, 0, 0);
    }
  }
  #pragma unroll
  for (int mf = 0; mf < 2; ++mf)
    #pragma unroll
    for (int nf = 0; nf < 5; ++nf)
      #pragma unroll
      for (int reg = 0; reg < 4; ++reg)
        T[wid][mf * 16 + kc * 4 + reg][nf * 16 + fr] = acc2[mf][nf][reg];
  __syncthreads();
  #pragma unroll
  for (int i = 0; i < 40; ++i) {
    const int flat = i * 64 + lane;
    const int n = flat >> 5, ml = flat & 31;
    KVp[((size_t)bid * 80 + n) * 256 + m0w + ml] = T[wid][ml][n];
  }
}

// ======================== reduce KVp -> KVXT bf16 ===========================
__global__ __launch_bounds__(256) void reduce_kvxt_kernel(
    const float* __restrict__ KVp, unsigned short* __restrict__ KVXT)
{
  const int bh = blockIdx.x;
  const int m = threadIdx.x;
  for (int n = 0; n < 80; ++n) {
    float s = 0.f;
    #pragma unroll
    for (int c = 0; c < 8; ++c)
      s += KVp[((size_t)(bh * 8 + c) * 80 + n) * 256 + m];
    KVXT[((size_t)bh * 80 + n) * 256 + m] = f2bf(s);
  }
}

// ======================== FAVOR-Q (MFMA) ====================================
__global__ __launch_bounds__(512) void favor_q_mfma(
    const float* __restrict__ Q,
    const unsigned short* __restrict__ oThi, const unsigned short* __restrict__ oTlo,
    const unsigned short* __restrict__ KVXT, unsigned short* __restrict__ O)
{
  const int bid = blockIdx.x;
  const int bh = bid >> 4, chunk = bid & 15;
  const int b = bh >> 4, h = bh & 15;
  const int s0 = chunk * 256;
  const int tid = threadIdx.x, lane = tid & 63, wid = tid >> 6;
  const int fr = lane & 15, kc = lane >> 4;
  const int ws0 = s0 + wid * 32;

  __shared__ unsigned short KX[80][264];
  __shared__ unsigned short P[8][32][66];

  for (int i = tid; i < 80 * 256; i += 512)
    KX[i >> 8][i & 255] = KVXT[(size_t)bh * 80 * 256 + i];
  __syncthreads();

  s16x8 ahi[2][2], alo[2][2];
  float nrm[2];
  #pragma unroll
  for (int r = 0; r < 2; ++r) {
    float part = 0.f;
    #pragma unroll
    for (int ks = 0; ks < 2; ++ks) {
      const float* ap = Q + ((size_t)(b * 4096 + ws0 + r * 16 + fr)) * 1024 +
                        h * 64 + ks * 32 + kc * 8;
      const float4 f0 = ((const float4*)ap)[0];
      const float4 f1 = ((const float4*)ap)[1];
      float v[8] = {f0.x, f0.y, f0.z, f0.w, f1.x, f1.y, f1.z, f1.w};
      #pragma unroll
      for (int u = 0; u < 8; ++u) {
        part = fmaf(v[u], v[u], part);
        const unsigned short hh = f2bf(v[u]);
        ahi[r][ks][u] = (short)hh;
        alo[r][ks][u] = (short)f2bf(v[u] - bf2f(hh));
      }
    }
    part += __shfl_xor(part, 16);
    part += __shfl_xor(part, 32);
    nrm[r] = 0.5f * part;
  }

  f32x4 acc2[2][5];
  #pragma unroll
  for (int i = 0; i < 2; ++i)
    #pragma unroll
    for (int j = 0; j < 5; ++j) acc2[i][j] = f32x4{0.f, 0.f, 0.f, 0.f};

  for (int mc = 0; mc < 4; ++mc) {
    __syncthreads();
    #pragma unroll
    for (int r = 0; r < 2; ++r)
      #pragma unroll
      for (int c = 0; c < 4; ++c) {
        f32x4 s1 = f32x4{0.f, 0.f, 0.f, 0.f};
        #pragma unroll
        for (int ks = 0; ks < 2; ++ks) {
          const size_t off = (size_t)(mc * 64 + c * 16 + fr) * 64 + ks * 32 + kc * 8;
          const s16x8 bh1 = *(const s16x8*)(oThi + off);
          const s16x8 bl1 = *(const s16x8*)(oTlo + off);
          s1 = __builtin_amdgcn_mfma_f32_16x16x32_bf16(alo[r][ks], bh1, s1, 0, 0, 0);
          s1 = __builtin_amdgcn_mfma_f32_16x16x32_bf16(ahi[r][ks], bl1, s1, 0, 0, 0);
          s1 = __builtin_amdgcn_mfma_f32_16x16x32_bf16(ahi[r][ks], bh1, s1, 0, 0, 0);
        }
        #pragma unroll
        for (int reg = 0; reg < 4; ++reg) {
          const int sl = kc * 4 + reg;
          const float nn = __shfl(nrm[r], sl);
          const float p = __expf(s1[reg] - nn - 2.772588722239781f);
          P[wid][r * 16 + sl][c * 16 + fr] = f2bf(p);
        }
      }
    __syncthreads();
    #pragma unroll
    for (int ks2 = 0; ks2 < 2; ++ks2) {
      s16x8 b2[5];
      #pragma unroll
      for (int nf = 0; nf < 5; ++nf)
        b2[nf] = *(const s16x8*)&KX[nf * 16 + fr][mc * 64 + ks2 * 32 + kc * 8];
      #pragma unroll
      for (int r = 0; r < 2; ++r) {
        const s16x8 a2 = *(const s16x8*)&P[wid][r * 16 + fr][ks2 * 32 + kc * 8];
        #pragma unroll
        for (int nf = 0; nf < 5; ++nf)
          acc2[r][nf] = __builtin_amdgcn_mfma_f32_16x16x32_bf16(a2, b2[nf], acc2[r][nf], 0, 0, 0);
      }
    }
  }
  #pragma unroll
  for (int r = 0; r < 2; ++r)
    #pragma unroll
    for (int reg = 0; reg < 4; ++reg) {
      const int s = ws0 + r * 16 + kc * 4 + reg;
      const float dv = __shfl(acc2[r][4][reg], lane & 48) + 1e-6f;
      #pragma unroll
      for (int nf = 0; nf < 4; ++nf)
        O[(size_t)(b * 4096 + s) * 1024 + h * 64 + nf * 16 + fr] =
            f2bf(acc2[r][nf][reg] / dv);
    }
}

// ======================== launcher ==========================================
extern "C" void kernel_launch(void* const* d_in, const int* in_sizes, int n_in,
                              void* d_out, int out_size, void* d_ws, size_t ws_size,
                              hipStream_t stream)
{
  const float* x      = (const float*)d_in[0];
  const float* conv_k = (const float*)d_in[1];
  const float* conv_b = (const float*)d_in[2];
  const float* rff_w  = (const float*)d_in[3];
  const float* rff_b  = (const float*)d_in[4];
  const float* proj_w = (const float*)d_in[5];
  const float* proj_b = (const float*)d_in[6];
  const float* omega  = (const float*)d_in[7];
  const float* lm     = (const float*)d_in[8];
  const float* out_w  = (const float*)d_in[9];
  const float* out_b  = (const float*)d_in[10];

  char* wsb = (char*)d_ws;
  size_t o = 0;
  auto alloc = [&](size_t bytes) {
    char* p = wsb + o;
    o = (o + bytes + 255) & ~(size_t)255;
    return p;
  };
  unsigned short* Wc_hi = (unsigned short*)alloc(4718592);
  unsigned short* Wc_lo = (unsigned short*)alloc(4718592);
  unsigned short* Wr_hi = (unsigned short*)alloc(4718592);
  unsigned short* Wr_lo = (unsigned short*)alloc(4718592);
  unsigned short* Wp    = (unsigned short*)alloc(4718592);
  unsigned short* Wo    = (unsigned short*)alloc(2097152);
  // R1: xhi/xlo during QKV loop; VT afterwards
  char* R1 = alloc(33554432);
  unsigned short* xhi = (unsigned short*)R1;
  unsigned short* xlo = (unsigned short*)(R1 + 16777216);
  unsigned short* VT  = (unsigned short*)R1;              // 20,971,520 B
  // R2: h hi/lo during loop; kny afterwards
  char* R2 = alloc(33554432);
  unsigned short* hhi = (unsigned short*)R2;
  unsigned short* hlo = (unsigned short*)(R2 + 16777216);
  float* kny = (float*)R2;                                // 33,554,432 B
  unsigned short* feats = (unsigned short*)alloc(12582912);
  float* Qb = (float*)alloc(33554432);
  float* Kb = (float*)alloc(33554432);
  float* Vb = (float*)alloc(33554432);
  float2* tab = (float2*)alloc(1048576);
  unsigned short* oThi = (unsigned short*)alloc(32768);
  unsigned short* oTlo = (unsigned short*)alloc(32768);
  // R3: KVp f32; Obf afterwards
  char* R3 = alloc(20971520);
  float* KVp = (float*)R3;
  unsigned short* Obf = (unsigned short*)R3;              // 16,777,216 B
  unsigned short* KVXT = (unsigned short*)alloc(1310720);

  dim3 blk(256);
  // prep: conversions & tables
  split_prep_kernel<<<4096, blk, 0, stream>>>(x, xhi, xlo, 1048576);
  wconv_kernel<0><<<dim3(12, 16, 3), blk, 0, stream>>>(conv_k, Wc_hi, Wc_lo);
  wconv_kernel<1><<<dim3(16, 4, 9),  blk, 0, stream>>>(rff_w, Wr_hi, Wr_lo);
  wconv_kernel<2><<<dim3(12, 16, 3), blk, 0, stream>>>(proj_w, Wp, nullptr);
  wconv_kernel<3><<<dim3(16, 16, 1), blk, 0, stream>>>(out_w, Wo, nullptr);
  omega_prep_kernel<<<64, blk, 0, stream>>>(omega, oThi, oTlo);
  rope_table_kernel<<<512, blk, 0, stream>>>(tab);

  float* qkv[3] = {Qb, Kb, Vb};
  for (int i = 0; i < 3; ++i) {
    gemm_mfma<0><<<dim3(8, 64), blk, 0, stream>>>(
        xhi, xlo, Wc_hi + (size_t)i * 786432, Wc_lo + (size_t)i * 786432,
        conv_b + i * 1024, nullptr, hhi, hlo, 8192, 1024, 768);
    gemm_mfma<1><<<dim3(6, 64), blk, 0, stream>>>(
        hhi, hlo, Wr_hi + (size_t)i * 786432, Wr_lo + (size_t)i * 786432,
        rff_b + i * 768, nullptr, feats, nullptr, 8192, 768, 1024);
    gemm_mfma<2><<<dim3(8, 64), blk, 0, stream>>>(
        feats, nullptr, Wp + (size_t)i * 786432, nullptr,
        proj_b + i * 1024, qkv[i], nullptr, nullptr, 8192, 1024, 768);
  }
  rope_apply_kernel<<<16384, blk, 0, stream>>>(tab, Qb, Kb);
  vt_kernel<<<dim3(32, 64), blk, 0, stream>>>(Vb, VT);
  vt_fill_kernel<<<8192, blk, 0, stream>>>(VT);
  nystrom_kernel<<<512, blk, 0, stream>>>(Kb, lm, kny);
  favor_k_mfma<<<256, dim3(512), 0, stream>>>(kny, oThi, oTlo, VT, KVp);
  reduce_kvxt_kernel<<<32, blk, 0, stream>>>(KVp, KVXT);
  favor_q_mfma<<<512, dim3(512), 0, stream>>>(Qb, oThi, oTlo, KVXT, Obf);
  gemm_mfma<2><<<dim3(8, 64), blk, 0, stream>>>(
      Obf, nullptr, Wo, nullptr, out_b, (float*)d_out, nullptr, nullptr,
      8192, 1024, 1024);
}